// Round 8
// baseline (957.574 us; speedup 1.0000x reference)
//
#include <hip/hip_runtime.h>
#include <hip/hip_bf16.h>

// ---------------- problem constants ----------------
#define SQ   64        // seq len
#define NN   1000      // nodes per graph
#define NT   64000     // total nodes
#define EE   128       // emb dim
#define EG   512000    // graph edges (no self loops)
#define ET   576000    // edges + self loops

// ---------------- workspace layout (bytes) ----------------
// common / fallback region (<71 MB)
#define WS_XA      0ull          // 32,768,000  float[NT*128]  x ping (mu lives here)
#define WS_XB      33000000ull   // 32,768,000  float[NT*128]  x pong (xl / la)
#define WS_ROWPTR  66000000ull   // 256,004     int[NT+1]
#define WS_CURSOR  66300000ull   // 256,000     int[NT]
#define WS_SRCS    66600000ull   // 2,304,000   int[ET]  (src node id, dst-grouped)
#define WS_INCL    69000000ull   // 256,000     int[NT]
#define WS_BSUM    69300000ull   // 1,024       int[250]
#define WS_BOFF    69302048ull   // 1,024       int[250]
#define WS_MODE    69304096ull   // 4           int
#define WS_WQA     70000000ull   // 262,144     float4[64*256]  (fallback LSTM)
#define WS_WQB     70262144ull   // 262,144     float4[64*256]  (fallback LSTM)
#define WS_AS      70600000ull   // 256         float[64]
#define WS_LOGIT2  70700000ull   // 256,000     float[NT]
// big-ws region: xCp aliases xB + CSR (disjoint lifetimes)
#define WS2_XC     33000000ull   // 131,072,000 float[NT*512]  gate preacts, PERMUTED
#define WS2_BFRAG  164100000ull  // 131,072     ushort bf16 Whh B-fragments (LSTM)
#define WS2_GHI    164300000ull  // 311,296     ushort GEMM W fragments (hi)
#define WS2_GLO    164650000ull  // 311,296     ushort GEMM W fragments (lo)
#define WS2_B512   165000000ull  // 2,048       float[512]     bih+bhh
#define WS2_MODE   165010000ull  // 4
#define WS2_AS     165020000ull  // 256
#define WS2_LOGIT2 165100000ull  // 256,000
#define WS2_NEED   165360000ull
// GEMM fragment sub-offsets (ushort elements within GHI/GLO)
#define G_W1    0        // 64x128  -> 8192
#define G_WL    8192     // 4 x 128x128 -> 16384 each
#define G_PROJ  73728    // 128x512 -> 65536
#define G_W7    139264   // 128x128 -> 16384

typedef __attribute__((ext_vector_type(8))) short short8;   // 8 bf16 (4 VGPRs)
typedef __attribute__((ext_vector_type(4))) float f32x4;

// ---------------- helpers ----------------
__device__ __forceinline__ float rdlane(float v, int l) {
    return __int_as_float(__builtin_amdgcn_readlane(__float_as_int(v), l));
}
__device__ __forceinline__ float sigm(float x) { return 1.0f / (1.0f + __expf(-x)); }
__device__ __forceinline__ float tanh_f(float x) {
    x = fminf(fmaxf(x, -30.0f), 30.0f);
    float e = __expf(2.0f * x);
    return (e - 1.0f) / (e + 1.0f);
}
__device__ __forceinline__ float tanh2(float x) {   // 2*sigmoid(2x)-1, inf-safe
    return 2.0f / (1.0f + __expf(-2.0f * x)) - 1.0f;
}
__device__ __forceinline__ ushort f2bf(float x) {   // round-to-nearest-even bf16
    unsigned u = __float_as_uint(x);
    unsigned r = (u + 0x7FFFu + ((u >> 16) & 1u)) >> 16;
    return (ushort)r;
}
__device__ __forceinline__ float bf2f(ushort h) {
    return __uint_as_float(((unsigned)h) << 16);
}

// ---------------- reachable dtype detection ----------------
__global__ void detect_mode_k(const unsigned char* __restrict__ p, int* __restrict__ mode) {
    __shared__ int f0, f3;
    const int t = threadIdx.x;
    if (t == 0) { f0 = 0; f3 = 0; }
    __syncthreads();
    int l0 = 0, l3 = 0;
    for (int i = t; i < 16000; i += 256) {
        if (p[4 * i])     l0 = 1;
        if (p[4 * i + 3]) l3 = 1;
    }
    if (l0) atomicOr(&f0, 1);
    if (l3) atomicOr(&f3, 1);
    __syncthreads();
    if (t == 0) {
        int m;
        if (f0 && f3)      m = 1;  // bool bytes
        else if (f0)       m = 0;  // int32
        else               m = 2;  // float32
        *mode = m;
    }
}

// ---------------- CSR construction (dst-grouped src list; built once) ----------------
__global__ void zero_ints_k(int* __restrict__ p, int n) {
    int i = blockIdx.x * 256 + threadIdx.x;
    if (i < n) p[i] = 0;
}
__global__ void hist_k(const int* __restrict__ ei, int* __restrict__ deg) {
    int e = blockIdx.x * 256 + threadIdx.x;
    if (e < ET) {
        int d = (e < EG) ? ei[EG + e] : (e - EG);
        atomicAdd(deg + d, 1);
    }
}
__global__ void scan1_k(const int* __restrict__ deg, int* __restrict__ incl, int* __restrict__ bsum) {
    __shared__ int sh[256];
    const int t = threadIdx.x;
    const int i = blockIdx.x * 256 + t;
    sh[t] = deg[i];
    __syncthreads();
    for (int o = 1; o < 256; o <<= 1) {
        int add = (t >= o) ? sh[t - o] : 0;
        __syncthreads();
        sh[t] += add;
        __syncthreads();
    }
    incl[i] = sh[t];
    if (t == 255) bsum[blockIdx.x] = sh[255];
}
__global__ void scan2_k(const int* __restrict__ bsum, int* __restrict__ boff) {
    __shared__ int sh[256];
    const int t = threadIdx.x;
    int v = (t < 250) ? bsum[t] : 0;
    sh[t] = v;
    __syncthreads();
    for (int o = 1; o < 256; o <<= 1) {
        int add = (t >= o) ? sh[t - o] : 0;
        __syncthreads();
        sh[t] += add;
        __syncthreads();
    }
    if (t < 250) boff[t] = sh[t] - v;   // exclusive
}
__global__ void scan3_k(const int* __restrict__ incl, const int* __restrict__ boff,
                        int* __restrict__ rowptr, int* __restrict__ cursor_deg) {
    const int i = blockIdx.x * 256 + threadIdx.x;
    int total = incl[i] + boff[blockIdx.x];
    int excl  = total - cursor_deg[i];
    rowptr[i] = excl;
    cursor_deg[i] = excl;                 // becomes fill cursor
    if (i == NT - 1) rowptr[NT] = total;
}
__global__ void fill_k(const int* __restrict__ ei, int* __restrict__ cursor, int* __restrict__ srcs) {
    int e = blockIdx.x * 256 + threadIdx.x;
    if (e < ET) {
        int s_, d_;
        if (e < EG) { s_ = ei[e]; d_ = ei[EG + e]; }
        else        { s_ = e - EG; d_ = s_; }
        int p = atomicAdd(cursor + d_, 1);
        srcs[p] = s_;
    }
}

// ---------------- bf16 split-precision W fragments for MFMA GEMM ----------------
__global__ void build_gfrag_k(const float* __restrict__ src, const int ks, const int ns,
                              const int K, ushort* __restrict__ dhi, ushort* __restrict__ dlo,
                              const int total) {
    int id = blockIdx.x * 256 + threadIdx.x;
    if (id < total) {
        int j = id & 7, lane = (id >> 3) & 63;
        int f = id >> 9;
        int KT = K >> 5;
        int nt = f / KT, kt = f - nt * KT;
        int n = nt * 16 + (lane & 15);
        int k = kt * 32 + ((lane >> 4) << 3) + j;
        float v = src[(size_t)k * ks + (size_t)n * ns];
        ushort h = f2bf(v);
        dhi[id] = h;
        dlo[id] = f2bf(v - bf2f(h));
    }
}
__global__ void bias512_k(const float* __restrict__ bih, const float* __restrict__ bhh,
                          float* __restrict__ b512) {
    int i = blockIdx.x * 256 + threadIdx.x;
    if (i < 512) b512[i] = bih[i] + bhh[i];
}

// ---------------- MFMA GEMM: out[M x N<=128] = x[M x K] @ W + bias ----------------
template <int KT>
__global__ __launch_bounds__(256) void gemm_mf(
    const float* __restrict__ x, const ushort* __restrict__ bhi,
    const ushort* __restrict__ blo, const float* __restrict__ bias,
    float* __restrict__ out, const int ldout)
{
    constexpr int K = KT * 32;
    __shared__ __align__(16) ushort ahi_s[64 * 136];
    __shared__ __align__(16) ushort alo_s[64 * 136];
    const int t = threadIdx.x;
    const int w = t >> 6, lane = t & 63;
    const int quad = lane >> 4, col = lane & 15;
    const int row0 = blockIdx.x * 64;
    const int col0 = blockIdx.y * 128;

    {
        const int r  = t >> 2;
        const int kc = (t & 3) * (K / 4);
        const float* xr = x + (size_t)(row0 + r) * K + kc;
        ushort* dh = ahi_s + r * 136 + kc;
        ushort* dl = alo_s + r * 136 + kc;
#pragma unroll
        for (int k = 0; k < K / 4; k += 4) {
            float4 v = *(const float4*)(xr + k);
            ushort h0_ = f2bf(v.x), h1_ = f2bf(v.y), h2_ = f2bf(v.z), h3_ = f2bf(v.w);
            ushort l0_ = f2bf(v.x - bf2f(h0_)), l1_ = f2bf(v.y - bf2f(h1_));
            ushort l2_ = f2bf(v.z - bf2f(h2_)), l3_ = f2bf(v.w - bf2f(h3_));
            *(uint2*)(dh + k) = make_uint2((uint)h0_ | ((uint)h1_ << 16),
                                           (uint)h2_ | ((uint)h3_ << 16));
            *(uint2*)(dl + k) = make_uint2((uint)l0_ | ((uint)l1_ << 16),
                                           (uint)l2_ | ((uint)l3_ << 16));
        }
    }
    __syncthreads();

    short8 ah[KT], al[KT];
#pragma unroll
    for (int kt = 0; kt < KT; kt++) {
        const int off = (w * 16 + col) * 136 + kt * 32 + quad * 8;
        ah[kt] = *(const short8*)(ahi_s + off);
        al[kt] = *(const short8*)(alo_s + off);
    }

    f32x4 acc[8];
#pragma unroll
    for (int q = 0; q < 8; q++) acc[q] = (f32x4){0.f, 0.f, 0.f, 0.f};

#pragma unroll
    for (int q = 0; q < 8; q++) {
#pragma unroll
        for (int kt = 0; kt < KT; kt++) {
            const int f = ((((col0 >> 4) + q) * KT + kt) * 64 + lane) * 8;
            short8 bh = *(const short8*)(bhi + f);
            short8 bl = *(const short8*)(blo + f);
            acc[q] = __builtin_amdgcn_mfma_f32_16x16x32_bf16(ah[kt], bh, acc[q], 0, 0, 0);
            acc[q] = __builtin_amdgcn_mfma_f32_16x16x32_bf16(al[kt], bh, acc[q], 0, 0, 0);
            acc[q] = __builtin_amdgcn_mfma_f32_16x16x32_bf16(ah[kt], bl, acc[q], 0, 0, 0);
        }
    }

#pragma unroll
    for (int q = 0; q < 8; q++) {
        float bv = bias[col0 + q * 16 + col];
#pragma unroll
        for (int r = 0; r < 4; r++) {
            out[(size_t)(row0 + w * 16 + quad * 4 + r) * ldout + col0 + q * 16 + col]
                = acc[q][r] + bv;
        }
    }
}

// ---------------- MFMA projection GEMM -> permuted xCp ----------------
// out layout: xCp[(row*64 + c)*8 + qg], c = gate&63, qg = gate>>6.
// One block covers all N=512 (32 n-tiles) so L2 merges the strided writes.
__global__ __launch_bounds__(256) void gemm_xcp(
    const float* __restrict__ x, const ushort* __restrict__ bhi,
    const ushort* __restrict__ blo, const float* __restrict__ b512,
    float* __restrict__ xCp)
{
    __shared__ __align__(16) ushort ahi_s[64 * 136];
    __shared__ __align__(16) ushort alo_s[64 * 136];
    const int t = threadIdx.x;
    const int w = t >> 6, lane = t & 63;
    const int quad = lane >> 4, col = lane & 15;
    const int row0 = blockIdx.x * 64;

    {
        const int r  = t >> 2;
        const int kc = (t & 3) * 32;
        const float* xr = x + (size_t)(row0 + r) * 128 + kc;
        ushort* dh = ahi_s + r * 136 + kc;
        ushort* dl = alo_s + r * 136 + kc;
#pragma unroll
        for (int k = 0; k < 32; k += 4) {
            float4 v = *(const float4*)(xr + k);
            ushort h0_ = f2bf(v.x), h1_ = f2bf(v.y), h2_ = f2bf(v.z), h3_ = f2bf(v.w);
            ushort l0_ = f2bf(v.x - bf2f(h0_)), l1_ = f2bf(v.y - bf2f(h1_));
            ushort l2_ = f2bf(v.z - bf2f(h2_)), l3_ = f2bf(v.w - bf2f(h3_));
            *(uint2*)(dh + k) = make_uint2((uint)h0_ | ((uint)h1_ << 16),
                                           (uint)h2_ | ((uint)h3_ << 16));
            *(uint2*)(dl + k) = make_uint2((uint)l0_ | ((uint)l1_ << 16),
                                           (uint)l2_ | ((uint)l3_ << 16));
        }
    }
    __syncthreads();

    short8 ah[4], al[4];
#pragma unroll
    for (int kt = 0; kt < 4; kt++) {
        const int off = (w * 16 + col) * 136 + kt * 32 + quad * 8;
        ah[kt] = *(const short8*)(ahi_s + off);
        al[kt] = *(const short8*)(alo_s + off);
    }

    for (int nt0 = 0; nt0 < 32; nt0 += 4) {
        f32x4 acc[4];
#pragma unroll
        for (int u = 0; u < 4; u++) acc[u] = (f32x4){0.f, 0.f, 0.f, 0.f};
#pragma unroll
        for (int kt = 0; kt < 4; kt++) {
#pragma unroll
            for (int u = 0; u < 4; u++) {
                const int f = (((nt0 + u) * 4 + kt) * 64 + lane) * 8;
                short8 bh = *(const short8*)(bhi + f);
                short8 bl = *(const short8*)(blo + f);
                acc[u] = __builtin_amdgcn_mfma_f32_16x16x32_bf16(ah[kt], bh, acc[u], 0, 0, 0);
                acc[u] = __builtin_amdgcn_mfma_f32_16x16x32_bf16(al[kt], bh, acc[u], 0, 0, 0);
                acc[u] = __builtin_amdgcn_mfma_f32_16x16x32_bf16(ah[kt], bl, acc[u], 0, 0, 0);
            }
        }
#pragma unroll
        for (int u = 0; u < 4; u++) {
            const int g = (nt0 + u) * 16 + col;
            const int c = g & 63, qg = g >> 6;
            const float bv = b512[g];
#pragma unroll
            for (int r = 0; r < 4; r++) {
                const int row = row0 + w * 16 + quad * 4 + r;
                xCp[((size_t)row * 64 + c) * 8 + qg] = acc[u][r] + bv;
            }
        }
    }
}

// ---------------- fp32 GEMM (fallback path only) ----------------
template <int K>
__global__ __launch_bounds__(256) void gemm3(
    const float* __restrict__ x, const float* __restrict__ W,
    const float* __restrict__ b, float* __restrict__ out)
{
    __shared__ float Wsh[64 * 128];
    __shared__ float xT[64][132];
    const int t = threadIdx.x;
    const int row0 = blockIdx.x * 128;
    const int cg = t & 15;
    const int rg = t >> 4;
    float4 acc[8][2];
#pragma unroll
    for (int r = 0; r < 8; r++) {
        acc[r][0] = make_float4(0.f, 0.f, 0.f, 0.f);
        acc[r][1] = make_float4(0.f, 0.f, 0.f, 0.f);
    }
    for (int k0 = 0; k0 < K; k0 += 64) {
        for (int i = t * 4; i < 64 * 128; i += 1024)
            *(float4*)(Wsh + i) = *(const float4*)(W + (size_t)k0 * 128 + i);
        for (int i = t * 4; i < 128 * 64; i += 1024) {
            int r = i >> 6, k = i & 63;
            float4 v = *(const float4*)(x + (size_t)(row0 + r) * K + k0 + k);
            xT[k + 0][r] = v.x; xT[k + 1][r] = v.y;
            xT[k + 2][r] = v.z; xT[k + 3][r] = v.w;
        }
        __syncthreads();
#pragma unroll 2
        for (int k = 0; k < 64; k++) {
            float4 w0 = *(const float4*)(Wsh + k * 128 + cg * 8);
            float4 w1 = *(const float4*)(Wsh + k * 128 + cg * 8 + 4);
            float4 x0 = *(const float4*)(&xT[k][rg * 8]);
            float4 x1 = *(const float4*)(&xT[k][rg * 8 + 4]);
            float xv[8] = {x0.x, x0.y, x0.z, x0.w, x1.x, x1.y, x1.z, x1.w};
#pragma unroll
            for (int r = 0; r < 8; r++) {
                acc[r][0].x += xv[r] * w0.x; acc[r][0].y += xv[r] * w0.y;
                acc[r][0].z += xv[r] * w0.z; acc[r][0].w += xv[r] * w0.w;
                acc[r][1].x += xv[r] * w1.x; acc[r][1].y += xv[r] * w1.y;
                acc[r][1].z += xv[r] * w1.z; acc[r][1].w += xv[r] * w1.w;
            }
        }
        __syncthreads();
    }
    float4 bv0 = *(const float4*)(b + cg * 8);
    float4 bv1 = *(const float4*)(b + cg * 8 + 4);
#pragma unroll
    for (int r = 0; r < 8; r++) {
        float4 o0, o1;
        o0.x = acc[r][0].x + bv0.x; o0.y = acc[r][0].y + bv0.y;
        o0.z = acc[r][0].z + bv0.z; o0.w = acc[r][0].w + bv0.w;
        o1.x = acc[r][1].x + bv1.x; o1.y = acc[r][1].y + bv1.y;
        o1.z = acc[r][1].z + bv1.z; o1.w = acc[r][1].w + bv1.w;
        float* op = out + (size_t)(row0 + rg * 8 + r) * 128 + cg * 8;
        *(float4*)(op) = o0;
        *(float4*)(op + 4) = o1;
    }
}

// ---------------- fused GATv2: 2-way pipelined online softmax ----------------
// One wave per dst node; half-waves = heads. Edges split into two independent
// online-softmax accumulator sets (2x ILP in the serial chain), merged at end.
// XCD swizzle: graph s handled by blocks with blockIdx%8==s%8 (L2 residency).
__global__ __launch_bounds__(256) void gat_fused_k(
    const float* __restrict__ xl, const int* __restrict__ rowptr,
    const int* __restrict__ srcs, const float* __restrict__ att,
    const float* __restrict__ bias, float* __restrict__ out, const int do_relu)
{
    const int lane = threadIdx.x & 63;
    const int b = blockIdx.x;
    const int g = b & 7;
    const int j = b >> 3;
    const int jq = j / 250;
    const int jj = j - jq * 250;
    const int s = g + 8 * jq;
    const int n = s * NN + jj * 4 + (threadIdx.x >> 6);

    const float2 a = *(const float2*)(att + lane * 2);
    const float2 xd = *(const float2*)(xl + (size_t)n * 128 + lane * 2);
    const int i0 = rowptr[n], i1 = rowptr[n + 1];

    float m0 = -1e30f, d0 = 0.f, ax0 = 0.f, ay0 = 0.f;
    float m1 = -1e30f, d1 = 0.f, ax1 = 0.f, ay1 = 0.f;

    int i = i0;
    int sv0 = srcs[i];
    int sv1 = (i + 1 < i1) ? srcs[i + 1] : 0;
    while (i + 1 < i1) {
        const float2 xs0 = *(const float2*)(xl + (size_t)sv0 * 128 + lane * 2);
        const float2 xs1 = *(const float2*)(xl + (size_t)sv1 * 128 + lane * 2);
        sv0 = (i + 2 < i1) ? srcs[i + 2] : 0;
        sv1 = (i + 3 < i1) ? srcs[i + 3] : 0;

        float u0 = xs0.x + xd.x, v0 = xs0.y + xd.y;
        float u1 = xs1.x + xd.x, v1 = xs1.y + xd.y;
        u0 = (u0 > 0.f) ? u0 : 0.2f * u0;  v0 = (v0 > 0.f) ? v0 : 0.2f * v0;
        u1 = (u1 > 0.f) ? u1 : 0.2f * u1;  v1 = (v1 > 0.f) ? v1 : 0.2f * v1;
        float p0 = u0 * a.x + v0 * a.y;
        float p1 = u1 * a.x + v1 * a.y;
        p0 += __shfl_xor(p0, 1, 32);   p1 += __shfl_xor(p1, 1, 32);
        p0 += __shfl_xor(p0, 2, 32);   p1 += __shfl_xor(p1, 2, 32);
        p0 += __shfl_xor(p0, 4, 32);   p1 += __shfl_xor(p1, 4, 32);
        p0 += __shfl_xor(p0, 8, 32);   p1 += __shfl_xor(p1, 8, 32);
        p0 += __shfl_xor(p0, 16, 32);  p1 += __shfl_xor(p1, 16, 32);

        float mn0 = fmaxf(m0, p0),  mn1 = fmaxf(m1, p1);
        float sc0 = __expf(m0 - mn0), sc1 = __expf(m1 - mn1);
        float w0 = __expf(p0 - mn0),  w1 = __expf(p1 - mn1);
        d0 = d0 * sc0 + w0;             d1 = d1 * sc1 + w1;
        ax0 = ax0 * sc0 + w0 * xs0.x;   ax1 = ax1 * sc1 + w1 * xs1.x;
        ay0 = ay0 * sc0 + w0 * xs0.y;   ay1 = ay1 * sc1 + w1 * xs1.y;
        m0 = mn0;                       m1 = mn1;
        i += 2;
    }
    if (i < i1) {   // odd leftover -> set0
        const float2 xs0 = *(const float2*)(xl + (size_t)sv0 * 128 + lane * 2);
        float u0 = xs0.x + xd.x, v0 = xs0.y + xd.y;
        u0 = (u0 > 0.f) ? u0 : 0.2f * u0;  v0 = (v0 > 0.f) ? v0 : 0.2f * v0;
        float p0 = u0 * a.x + v0 * a.y;
        p0 += __shfl_xor(p0, 1, 32);
        p0 += __shfl_xor(p0, 2, 32);
        p0 += __shfl_xor(p0, 4, 32);
        p0 += __shfl_xor(p0, 8, 32);
        p0 += __shfl_xor(p0, 16, 32);
        float mn0 = fmaxf(m0, p0);
        float sc0 = __expf(m0 - mn0), w0 = __expf(p0 - mn0);
        d0 = d0 * sc0 + w0;
        ax0 = ax0 * sc0 + w0 * xs0.x;
        ay0 = ay0 * sc0 + w0 * xs0.y;
        m0 = mn0;
    }
    // merge the two sets (empty set1: m1=-1e30 -> weight 0)
    float mm = fmaxf(m0, m1);
    float s0 = __expf(m0 - mm), s1 = __expf(m1 - mm);
    float den = d0 * s0 + d1 * s1;
    float ax = ax0 * s0 + ax1 * s1;
    float ay = ay0 * s0 + ay1 * s1;

    float2 bv = *(const float2*)(bias + lane * 2);
    float inv = 1.f / den;
    float ox = ax * inv + bv.x, oy = ay * inv + bv.y;
    if (do_relu) { ox = fmaxf(ox, 0.f); oy = fmaxf(oy, 0.f); }
    *(float2*)(out + (size_t)n * 128 + lane * 2) = make_float2(ox, oy);
}

// ---------------- LSTM weight packing (fallback path) ----------------
__global__ void build_wq_k(const float* __restrict__ Wih, const float* __restrict__ Whh,
                           float4* __restrict__ WQa, float4* __restrict__ WQb) {
    int id = blockIdx.x * 256 + threadIdx.x;
    if (id < 64 * 256) {
        int kp = id >> 8, t = id & 255;
        int j1 = t, j2 = t + 256;
        WQa[id] = make_float4(Wih[(size_t)j1 * 128 + 2 * kp], Whh[(size_t)j1 * 128 + 2 * kp],
                              Wih[(size_t)j1 * 128 + 2 * kp + 1], Whh[(size_t)j1 * 128 + 2 * kp + 1]);
        WQb[id] = make_float4(Wih[(size_t)j2 * 128 + 2 * kp], Whh[(size_t)j2 * 128 + 2 * kp],
                              Wih[(size_t)j2 * 128 + 2 * kp + 1], Whh[(size_t)j2 * 128 + 2 * kp + 1]);
    }
}

// ---------------- bf16 B-fragment pack of Whh (LSTM MFMA) ----------------
__global__ void build_bfrag_k(const float* __restrict__ Whh, ushort* __restrict__ Bfrag) {
    int id = blockIdx.x * 256 + threadIdx.x;    // 65536 ids
    if (id < 65536) {
        int j = id & 7, lane = (id >> 3) & 63, kt = (id >> 9) & 3, tile = id >> 11;
        int gate = tile * 16 + (lane & 15);
        int k = kt * 32 + ((lane >> 4) << 3) + j;
        Bfrag[id] = f2bf(Whh[(size_t)gate * 128 + k]);
    }
}

// ---- fallback LSTM (round-3, small-ws only) ----
#define LSTM_GROUP(buf, gbase)                                                     \
    _Pragma("unroll")                                                              \
    for (int i_ = 0; i_ < 4; i_++) {                                               \
        const int kp_ = (gbase) * 4 + i_;                                          \
        const float4 qa_ = buf[i_];                                                \
        const float4 qb_ = buf[4 + i_];                                            \
        _Pragma("unroll")                                                          \
        for (int n_ = 0; n_ < 4; n_++) {                                           \
            const float sx0_ = rdlane(xr[n_].x, kp_);                              \
            const float sh0_ = rdlane(hr[n_].x, kp_);                              \
            const float sx1_ = rdlane(xr[n_].y, kp_);                              \
            const float sh1_ = rdlane(hr[n_].y, kp_);                              \
            acc1[n_] += sx0_ * qa_.x + sh0_ * qa_.y + sx1_ * qa_.z + sh1_ * qa_.w; \
            acc2[n_] += sx0_ * qb_.x + sh0_ * qb_.y + sx1_ * qb_.z + sh1_ * qb_.w; \
        }                                                                          \
    }

__global__ __launch_bounds__(256, 1) void lstm_k(
    float* __restrict__ mu, const float4* __restrict__ WQa, const float4* __restrict__ WQb,
    const float* __restrict__ bih, const float* __restrict__ bhh,
    const float* __restrict__ h0, const float* __restrict__ c0,
    float* __restrict__ hT, float* __restrict__ cT)
{
    const int t = threadIdx.x, lane = t & 63;
    const int n0 = blockIdx.x * 4;
    __shared__ float hsh[4][128];
    __shared__ float gsh[4][512];
    const float b1 = bih[t] + bhh[t];
    const float b2 = bih[t + 256] + bhh[t + 256];
    float creg[2];
#pragma unroll
    for (int q = 0; q < 2; q++) {
        int id = t + 256 * q;
        creg[q] = c0[(size_t)(n0 + (id >> 7)) * 128 + (id & 127)];
    }
    for (int i = t; i < 512; i += 256)
        hsh[i >> 7][i & 127] = h0[(size_t)(n0 + (i >> 7)) * 128 + (i & 127)];

    const float4* pA = WQa + t;
    const float4* pB = WQb + t;

    float2 xr[4], xnx[4];
#pragma unroll
    for (int n = 0; n < 4; n++)
        xr[n] = *(const float2*)(mu + (size_t)n0 * 128 + n * 128 + lane * 2);
    __syncthreads();

    for (int s = 0; s < SQ; s++) {
        float* xrow = mu + ((size_t)s * NN + n0) * 128;
        float2 hr[4];
#pragma unroll
        for (int n = 0; n < 4; n++) hr[n] = *(const float2*)(&hsh[n][lane * 2]);

        float4 bufA[8], bufB[8];
#pragma unroll
        for (int i = 0; i < 4; i++) { bufA[i] = pA[i * 256]; bufA[4 + i] = pB[i * 256]; }

        if (s + 1 < SQ) {
            const float* xrow2 = mu + ((size_t)(s + 1) * NN + n0) * 128;
#pragma unroll
            for (int n = 0; n < 4; n++) xnx[n] = *(const float2*)(xrow2 + n * 128 + lane * 2);
        }

        float acc1[4], acc2[4];
#pragma unroll
        for (int n = 0; n < 4; n++) { acc1[n] = b1; acc2[n] = b2; }

        for (int g = 0; g < 16; g += 2) {
#pragma unroll
            for (int i = 0; i < 4; i++) {
                bufB[i]     = pA[((g + 1) * 4 + i) * 256];
                bufB[4 + i] = pB[((g + 1) * 4 + i) * 256];
            }
            LSTM_GROUP(bufA, g)
            if (g < 14) {
#pragma unroll
                for (int i = 0; i < 4; i++) {
                    bufA[i]     = pA[((g + 2) * 4 + i) * 256];
                    bufA[4 + i] = pB[((g + 2) * 4 + i) * 256];
                }
            }
            LSTM_GROUP(bufB, g + 1)
        }

#pragma unroll
        for (int n = 0; n < 4; n++) { gsh[n][t] = acc1[n]; gsh[n][t + 256] = acc2[n]; }
        __syncthreads();
#pragma unroll
        for (int q = 0; q < 2; q++) {
            int id = t + 256 * q;
            int n = id >> 7, e = id & 127;
            float iv = gsh[n][e], fv = gsh[n][128 + e];
            float gv = gsh[n][256 + e], ov = gsh[n][384 + e];
            float c = sigm(fv) * creg[q] + sigm(iv) * tanh_f(gv);
            float h = sigm(ov) * tanh_f(c);
            creg[q] = c;
            hsh[n][e] = h;
            xrow[n * 128 + e] = h;
            if (s == SQ - 1) {
                hT[(size_t)(n0 + n) * 128 + e] = h;
                cT[(size_t)(n0 + n) * 128 + e] = c;
            }
        }
#pragma unroll
        for (int n = 0; n < 4; n++) xr[n] = xnx[n];
        __syncthreads();
    }
}

// ---------------- MFMA LSTM v3 (big-ws path) ----------------
// 63 blocks x 16 nodes (r6's full-MFMA config) + r7's single-barrier ping-pong
// + step-ahead WIDE xCp loads (2x float4/node, permuted layout) + cheap tanh.
__global__ __launch_bounds__(256, 1) void lstm4_k(
    float* __restrict__ mu, const float* __restrict__ xCp,
    const ushort* __restrict__ Bfrag,
    const float* __restrict__ h0, const float* __restrict__ c0,
    float* __restrict__ hT, float* __restrict__ cT)
{
    const int t = threadIdx.x;
    const int w = t >> 6, lane = t & 63;
    const int quad = lane >> 4, col = lane & 15;
    const int n0 = blockIdx.x * 16;
    const int c_ = w * 16 + col;                  // 0..63 channel-within-64

    __shared__ __align__(16) ushort hbuf[2][2][16 * 136];   // [pingpong][hi/lo]

    // B fragments -> registers (constant all 64 steps)
    short8 bf[8][4];
#pragma unroll
    for (int q = 0; q < 8; q++)
#pragma unroll
        for (int kt = 0; kt < 4; kt++) {
            int tile = q * 4 + w;
            bf[q][kt] = *(const short8*)(Bfrag + (((tile * 4 + kt) * 64 + lane) << 3));
        }

    // init h into both buffers, c into regs
    for (int i = t; i < 2048; i += 256) {
        int node = i >> 7, e = i & 127;
        int gn = n0 + node;
        float v = (gn < NN) ? h0[(size_t)gn * 128 + e] : 0.f;
        ushort hh = f2bf(v), hl = f2bf(v - bf2f(hh));
        hbuf[0][0][node * 136 + e] = hh; hbuf[0][1][node * 136 + e] = hl;
        hbuf[1][0][node * 136 + e] = hh; hbuf[1][1][node * 136 + e] = hl;
    }
    float cst[8];
#pragma unroll
    for (int q = 0; q < 2; q++)
#pragma unroll
        for (int r = 0; r < 4; r++) {
            int gn = n0 + quad * 4 + r;
            cst[q * 4 + r] = (gn < NN) ? c0[(size_t)gn * 128 + (q * 64 + c_)] : 0.f;
        }

    // preload step-0 xCp (2x float4 per node)
    float4 xca[4], xcb[4], xna[4], xnb[4];
#pragma unroll
    for (int r = 0; r < 4; r++) {
        int gn = n0 + quad * 4 + r; if (gn >= NN) gn = NN - 1;
        const float* gb = xCp + ((size_t)gn * 64 + c_) * 8;
        xca[r] = *(const float4*)(gb);
        xcb[r] = *(const float4*)(gb + 4);
    }
    __syncthreads();

    int p = 0;
    for (int s = 0; s < SQ; s++) {
        // prefetch next step's xCp (consumed next iteration)
        if (s + 1 < SQ) {
#pragma unroll
            for (int r = 0; r < 4; r++) {
                int gn = n0 + quad * 4 + r; if (gn >= NN) gn = NN - 1;
                const float* gb = xCp + (((size_t)(s + 1) * NN + gn) * 64 + c_) * 8;
                xna[r] = *(const float4*)(gb);
                xnb[r] = *(const float4*)(gb + 4);
            }
        }

        // A fragments from current buffer (row = node = lane&15)
        short8 ahi[4], alo[4];
#pragma unroll
        for (int kt = 0; kt < 4; kt++) {
            ahi[kt] = *(const short8*)(&hbuf[p][0][col * 136 + kt * 32 + quad * 8]);
            alo[kt] = *(const short8*)(&hbuf[p][1][col * 136 + kt * 32 + quad * 8]);
        }

        f32x4 acc[8];
#pragma unroll
        for (int q = 0; q < 8; q++) acc[q] = (f32x4){0.f, 0.f, 0.f, 0.f};
#pragma unroll
        for (int kt = 0; kt < 4; kt++) {
#pragma unroll
            for (int q = 0; q < 8; q++) {
                acc[q] = __builtin_amdgcn_mfma_f32_16x16x32_bf16(ahi[kt], bf[q][kt], acc[q], 0, 0, 0);
                acc[q] = __builtin_amdgcn_mfma_f32_16x16x32_bf16(alo[kt], bf[q][kt], acc[q], 0, 0, 0);
            }
        }

        // epilogue -> OTHER buffer (no WAR on hbuf[p]; single barrier at end)
        float* mus = mu + (size_t)s * (NN * 128);
        const int pn = p ^ 1;
#pragma unroll
        for (int r = 0; r < 4; r++) {
            const int node = quad * 4 + r;
            const int gn = n0 + node;
            // q = 0 cell (channels 0..63): gates qg = 0(i),2(f),4(g),6(o)
            {
                float iv = acc[0][r] + xca[r].x;
                float fv = acc[2][r] + xca[r].z;
                float gv = acc[4][r] + xcb[r].x;
                float ov = acc[6][r] + xcb[r].z;
                float c = sigm(fv) * cst[r] + sigm(iv) * tanh2(gv);
                float h = sigm(ov) * tanh2(c);
                cst[r] = c;
                int e = c_;
                ushort hh = f2bf(h);
                hbuf[pn][0][node * 136 + e] = hh;
                hbuf[pn][1][node * 136 + e] = f2bf(h - bf2f(hh));
                if (gn < NN) {
                    mus[(size_t)gn * 128 + e] = h;
                    if (s == SQ - 1) {
                        hT[(size_t)gn * 128 + e] = h;
                        cT[(size_t)gn * 128 + e] = c;
                    }
                }
            }
            // q = 1 cell (channels 64..127): gates qg = 1,3,5,7
            {
                float iv = acc[1][r] + xca[r].y;
                float fv = acc[3][r] + xca[r].w;
                float gv = acc[5][r] + xcb[r].y;
                float ov = acc[7][r] + xcb[r].w;
                float c = sigm(fv) * cst[4 + r] + sigm(iv) * tanh2(gv);
                float h = sigm(ov) * tanh2(c);
                cst[4 + r] = c;
                int e = 64 + c_;
                ushort hh = f2bf(h);
                hbuf[pn][0][node * 136 + e] = hh;
                hbuf[pn][1][node * 136 + e] = f2bf(h - bf2f(hh));
                if (gn < NN) {
                    mus[(size_t)gn * 128 + e] = h;
                    if (s == SQ - 1) {
                        hT[(size_t)gn * 128 + e] = h;
                        cT[(size_t)gn * 128 + e] = c;
                    }
                }
            }
        }
#pragma unroll
        for (int r = 0; r < 4; r++) { xca[r] = xna[r]; xcb[r] = xnb[r]; }
        p = pn;
        __syncthreads();
    }
}

// ---------------- head: meanpool -> gs -> A[s] ----------------
__global__ __launch_bounds__(256) void meanpool_gs_k(
    const float* __restrict__ mu, const float* __restrict__ W6,
    const float* __restrict__ b6, const float* __restrict__ w5,
    float* __restrict__ A)
{
    const int s = blockIdx.x, t = threadIdx.x;
    const int cg = t & 31, ns = t >> 5;   // ch group of 4; 8 node-slots
    __shared__ float4 red4[8][33];
    __shared__ float mp[128];
    __shared__ float red[256];
    float4 acc = make_float4(0.f, 0.f, 0.f, 0.f);
    for (int n = ns; n < NN; n += 8) {
        float4 v = *(const float4*)(mu + ((size_t)s * NN + n) * 128 + cg * 4);
        acc.x += v.x; acc.y += v.y; acc.z += v.z; acc.w += v.w;
    }
    red4[ns][cg] = acc;
    __syncthreads();
    if (t < 32) {
        float4 r = red4[0][t];
#pragma unroll
        for (int k = 1; k < 8; k++) {
            float4 v = red4[k][t];
            r.x += v.x; r.y += v.y; r.z += v.z; r.w += v.w;
        }
        mp[t * 4 + 0] = r.x * 0.001f;
        mp[t * 4 + 1] = r.y * 0.001f;
        mp[t * 4 + 2] = r.z * 0.001f;
        mp[t * 4 + 3] = r.w * 0.001f;
    }
    __syncthreads();
    float g = 0.f;
    if (t < 128) {
        g = b6[t];
        for (int k = 0; k < 128; k++) g += mp[k] * W6[(size_t)k * 128 + t];
        g = fmaxf(g, 0.f) * w5[t];
    }
    red[t] = g;
    __syncthreads();
    for (int o = 128; o > 0; o >>= 1) {
        if (t < o) red[t] += red[t + o];
        __syncthreads();
    }
    if (t == 0) A[s] = red[0];
}

// ---------------- head: logit2[row] ----------------
__global__ __launch_bounds__(256) void rowdot_k(
    const float* __restrict__ la, const float* __restrict__ w5,
    const float* __restrict__ b5, const float* __restrict__ A,
    float* __restrict__ out)
{
    const int lane = threadIdx.x & 63;
    const int row = blockIdx.x * 4 + (threadIdx.x >> 6);
    float2 v = *(const float2*)(la + (size_t)row * 128 + lane * 2);
    float2 w = *(const float2*)(w5 + 128 + lane * 2);
    float x = fmaxf(v.x, 0.f) * w.x + fmaxf(v.y, 0.f) * w.y;
#pragma unroll
    for (int o = 32; o; o >>= 1) x += __shfl_down(x, o);
    if (lane == 0) out[row] = x + A[row / NN] + b5[0];
}

// ---------------- masked softmax per sequence step ----------------
__device__ __forceinline__ bool reach_at(const void* reach, int mode, int idx) {
    if (mode == 0) return ((const int*)reach)[idx] != 0;
    if (mode == 1) return ((const unsigned char*)reach)[idx] != 0;
    return ((const float*)reach)[idx] != 0.f;
}
__global__ __launch_bounds__(256) void softmax_k(
    const float* __restrict__ lg, const void* __restrict__ reach,
    const int* __restrict__ mode, float* __restrict__ prob)
{
    const int s = blockIdx.x, t = threadIdx.x;
    const int m = *mode;
    __shared__ float red[256];
    float mx = -1e30f;
    for (int i = t; i < NN; i += 256) {
        int idx = s * NN + i;
        if (reach_at(reach, m, idx)) mx = fmaxf(mx, lg[idx]);
    }
    red[t] = mx;
    __syncthreads();
    for (int o = 128; o; o >>= 1) {
        if (t < o) red[t] = fmaxf(red[t], red[t + o]);
        __syncthreads();
    }
    mx = red[0];
    __syncthreads();
    float sum = 0.f;
    for (int i = t; i < NN; i += 256) {
        int idx = s * NN + i;
        float v = reach_at(reach, m, idx) ? __expf(lg[idx] - mx) : 0.f;
        prob[idx] = v;
        sum += v;
    }
    red[t] = sum;
    __syncthreads();
    for (int o = 128; o; o >>= 1) {
        if (t < o) red[t] += red[t + o];
        __syncthreads();
    }
    float inv = 1.f / red[0];
    for (int i = t; i < NN; i += 256) prob[s * NN + i] *= inv;
}

// ---------------- driver ----------------
extern "C" void kernel_launch(void* const* d_in, const int* in_sizes, int n_in,
                              void* d_out, int out_size, void* d_ws, size_t ws_size,
                              hipStream_t stream) {
    const float* nfm   = (const float*)d_in[0];
    const int*   ei    = (const int*)d_in[1];
    const void*  reach = d_in[2];
    const float* h0    = (const float*)d_in[3];
    const float* c0    = (const float*)d_in[4];
    const float* W1    = (const float*)d_in[5];
    const float* b1    = (const float*)d_in[6];
    const float* att1  = (const float*)d_in[7];
    const float* bias1 = (const float*)d_in[8];
    const float* Wl    = (const float*)d_in[9];
    const float* bl    = (const float*)d_in[10];
    const float* attl  = (const float*)d_in[11];
    const float* biasl = (const float*)d_in[12];
    const float* Wih   = (const float*)d_in[13];
    const float* Whh   = (const float*)d_in[14];
    const float* bih   = (const float*)d_in[15];
    const float* bhh   = (const float*)d_in[16];
    const float* W6    = (const float*)d_in[17];
    const float* b6    = (const float*)d_in[18];
    const float* W7    = (const float*)d_in[19];
    const float* b7    = (const float*)d_in[20];
    const float* w5    = (const float*)d_in[21];
    const float* b5    = (const float*)d_in[22];

    char* ws = (char*)d_ws;
    const bool bigws = (ws_size >= WS2_NEED);

    float*  xA     = (float*)(ws + WS_XA);
    float*  xB     = (float*)(ws + WS_XB);
    int*    rowptr = (int*)(ws + WS_ROWPTR);
    int*    cursor = (int*)(ws + WS_CURSOR);
    int*    srcs   = (int*)(ws + WS_SRCS);
    int*    incl   = (int*)(ws + WS_INCL);
    int*    bsum   = (int*)(ws + WS_BSUM);
    int*    boff   = (int*)(ws + WS_BOFF);
    int*    modep  = bigws ? (int*)(ws + WS2_MODE)     : (int*)(ws + WS_MODE);
    float*  As     = bigws ? (float*)(ws + WS2_AS)     : (float*)(ws + WS_AS);
    float*  logit2 = bigws ? (float*)(ws + WS2_LOGIT2) : (float*)(ws + WS_LOGIT2);
    // big-ws extras
    float*  xCp    = (float*)(ws + WS2_XC);
    ushort* Bfrag  = (ushort*)(ws + WS2_BFRAG);
    ushort* ghi    = (ushort*)(ws + WS2_GHI);
    ushort* glo    = (ushort*)(ws + WS2_GLO);
    float*  b512   = (float*)(ws + WS2_B512);
    // fallback extras
    float4* WQa    = (float4*)(ws + WS_WQA);
    float4* WQb    = (float4*)(ws + WS_WQB);

    float* prob = (float*)d_out;
    float* hT   = (float*)d_out + 64000;
    float* cT   = (float*)d_out + 192000;

    // setup
    detect_mode_k<<<1, 256, 0, stream>>>((const unsigned char*)reach, modep);
    zero_ints_k<<<250, 256, 0, stream>>>(cursor, NT);
    hist_k<<<2250, 256, 0, stream>>>(ei, cursor);
    scan1_k<<<250, 256, 0, stream>>>(cursor, incl, bsum);
    scan2_k<<<1, 256, 0, stream>>>(bsum, boff);
    scan3_k<<<250, 256, 0, stream>>>(incl, boff, rowptr, cursor);
    fill_k<<<2250, 256, 0, stream>>>(ei, cursor, srcs);
    if (bigws) {
        build_bfrag_k<<<256, 256, 0, stream>>>(Whh, Bfrag);
        bias512_k<<<2, 256, 0, stream>>>(bih, bhh, b512);
        build_gfrag_k<<<32, 256, 0, stream>>>(W1, 128, 1, 64, ghi + G_W1, glo + G_W1, 8192);
        for (int i = 0; i < 4; i++)
            build_gfrag_k<<<64, 256, 0, stream>>>(Wl + (size_t)i * 16384, 128, 1, 128,
                                                  ghi + G_WL + i * 16384, glo + G_WL + i * 16384, 16384);
        build_gfrag_k<<<256, 256, 0, stream>>>(Wih, 1, 128, 128, ghi + G_PROJ, glo + G_PROJ, 65536);
        build_gfrag_k<<<64, 256, 0, stream>>>(W7, 128, 1, 128, ghi + G_W7, glo + G_W7, 16384);
    } else {
        build_wq_k<<<64, 256, 0, stream>>>(Wih, Whh, WQa, WQb);
    }

    // 5 GATv2 layers: gemm (x->xB), fused logits+softmax+aggregate (xB->xA)
    for (int l = 0; l < 5; l++) {
        if (bigws) {
            if (l == 0)
                gemm_mf<2><<<dim3(1000, 1), 256, 0, stream>>>(nfm, ghi + G_W1, glo + G_W1, b1, xB, 128);
            else
                gemm_mf<4><<<dim3(1000, 1), 256, 0, stream>>>(xA, ghi + G_WL + (l - 1) * 16384,
                                                              glo + G_WL + (l - 1) * 16384,
                                                              bl + (l - 1) * 128, xB, 128);
        } else {
            if (l == 0)
                gemm3<64><<<500, 256, 0, stream>>>(nfm, W1, b1, xB);
            else
                gemm3<128><<<500, 256, 0, stream>>>(xA, Wl + (size_t)(l - 1) * 128 * 128,
                                                    bl + (l - 1) * 128, xB);
        }
        const float* att  = (l == 0) ? att1  : attl  + (l - 1) * 128;
        const float* bias = (l == 0) ? bias1 : biasl + (l - 1) * 128;
        gat_fused_k<<<16000, 256, 0, stream>>>(xB, rowptr, srcs, att, bias, xA,
                                               (l < 4) ? 1 : 0);
    }

    // LSTM
    if (bigws) {
        gemm_xcp<<<1000, 256, 0, stream>>>(xA, ghi + G_PROJ, glo + G_PROJ, b512, xCp);
        lstm4_k<<<63, 256, 0, stream>>>(xA, xCp, Bfrag, h0, c0, hT, cT);
    } else {
        lstm_k<<<250, 256, 0, stream>>>(xA, WQa, WQb, bih, bhh, h0, c0, hT, cT);
    }

    // head
    meanpool_gs_k<<<64, 256, 0, stream>>>(xA, W6, b6, w5, As);
    if (bigws)
        gemm_mf<4><<<dim3(1000, 1), 256, 0, stream>>>(xA, ghi + G_W7, glo + G_W7, b7, xB, 128);
    else
        gemm3<128><<<500, 256, 0, stream>>>(xA, W7, b7, xB);
    rowdot_k<<<16000, 256, 0, stream>>>(xB, w5, b5, As, logit2);
    softmax_k<<<64, 256, 0, stream>>>(logit2, reach, modep, prob);
}

// Round 9
// 927.427 us; speedup vs baseline: 1.0325x; 1.0325x over previous
//
#include <hip/hip_runtime.h>
#include <hip/hip_bf16.h>

// ---------------- problem constants ----------------
#define SQ   64        // seq len
#define NN   1000      // nodes per graph
#define NT   64000     // total nodes
#define EE   128       // emb dim
#define EG   512000    // graph edges (no self loops)
#define ET   576000    // edges + self loops

// ---------------- workspace layout (bytes) ----------------
// common / fallback region (<71 MB)
#define WS_XA      0ull          // 32,768,000  float[NT*128]  x ping (mu lives here)
#define WS_XB      33000000ull   // 32,768,000  float[NT*128]  x pong (xl / la)
#define WS_ROWPTR  66000000ull   // 256,004     int[NT+1]
#define WS_CURSOR  66300000ull   // 256,000     int[NT]
#define WS_SRCS    66600000ull   // 2,304,000   int[ET]  (src node id, dst-grouped)
#define WS_INCL    69000000ull   // 256,000     int[NT]
#define WS_BSUM    69300000ull   // 1,024       int[250]
#define WS_BOFF    69302048ull   // 1,024       int[250]
#define WS_MODE    69304096ull   // 4           int
#define WS_WQA     70000000ull   // 262,144     float4[64*256]  (fallback LSTM)
#define WS_WQB     70262144ull   // 262,144     float4[64*256]  (fallback LSTM)
#define WS_AS      70600000ull   // 256         float[64]
#define WS_LOGIT2  70700000ull   // 256,000     float[NT]
// big-ws region: xC aliases xB + CSR (disjoint lifetimes)
#define WS2_XC     33000000ull   // 131,072,000 float[NT*512]  gate preacts (row-major)
#define WS2_BFRAG  164100000ull  // 131,072     ushort bf16 Whh B-fragments (LSTM)
#define WS2_GHI    164300000ull  // 311,296     ushort GEMM W fragments (hi)
#define WS2_GLO    164650000ull  // 311,296     ushort GEMM W fragments (lo)
#define WS2_B512   165000000ull  // 2,048       float[512]     bih+bhh
#define WS2_MODE   165010000ull  // 4
#define WS2_AS     165020000ull  // 256
#define WS2_LOGIT2 165100000ull  // 256,000
#define WS2_NEED   165360000ull
// GEMM fragment sub-offsets (ushort elements within GHI/GLO)
#define G_W1    0        // 64x128  -> 8192
#define G_WL    8192     // 4 x 128x128 -> 16384 each
#define G_PROJ  73728    // 128x512 -> 65536
#define G_W7    139264   // 128x128 -> 16384

typedef __attribute__((ext_vector_type(8))) short short8;   // 8 bf16 (4 VGPRs)
typedef __attribute__((ext_vector_type(4))) float f32x4;

// ---------------- helpers ----------------
__device__ __forceinline__ float rdlane(float v, int l) {
    return __int_as_float(__builtin_amdgcn_readlane(__float_as_int(v), l));
}
__device__ __forceinline__ float sigm(float x) { return 1.0f / (1.0f + __expf(-x)); }
__device__ __forceinline__ float tanh_f(float x) {
    x = fminf(fmaxf(x, -30.0f), 30.0f);
    float e = __expf(2.0f * x);
    return (e - 1.0f) / (e + 1.0f);
}
__device__ __forceinline__ float tanh2(float x) {   // 2*sigmoid(2x)-1, inf-safe
    return 2.0f / (1.0f + __expf(-2.0f * x)) - 1.0f;
}
__device__ __forceinline__ ushort f2bf(float x) {   // round-to-nearest-even bf16
    unsigned u = __float_as_uint(x);
    unsigned r = (u + 0x7FFFu + ((u >> 16) & 1u)) >> 16;
    return (ushort)r;
}
__device__ __forceinline__ float bf2f(ushort h) {
    return __uint_as_float(((unsigned)h) << 16);
}

// ---------------- reachable dtype detection ----------------
__global__ void detect_mode_k(const unsigned char* __restrict__ p, int* __restrict__ mode) {
    __shared__ int f0, f3;
    const int t = threadIdx.x;
    if (t == 0) { f0 = 0; f3 = 0; }
    __syncthreads();
    int l0 = 0, l3 = 0;
    for (int i = t; i < 16000; i += 256) {
        if (p[4 * i])     l0 = 1;
        if (p[4 * i + 3]) l3 = 1;
    }
    if (l0) atomicOr(&f0, 1);
    if (l3) atomicOr(&f3, 1);
    __syncthreads();
    if (t == 0) {
        int m;
        if (f0 && f3)      m = 1;  // bool bytes
        else if (f0)       m = 0;  // int32
        else               m = 2;  // float32
        *mode = m;
    }
}

// ---------------- CSR construction (dst-grouped src list; built once) ----------------
__global__ void zero_ints_k(int* __restrict__ p, int n) {
    int i = blockIdx.x * 256 + threadIdx.x;
    if (i < n) p[i] = 0;
}
__global__ void hist_k(const int* __restrict__ ei, int* __restrict__ deg) {
    int e = blockIdx.x * 256 + threadIdx.x;
    if (e < ET) {
        int d = (e < EG) ? ei[EG + e] : (e - EG);
        atomicAdd(deg + d, 1);
    }
}
__global__ void scan1_k(const int* __restrict__ deg, int* __restrict__ incl, int* __restrict__ bsum) {
    __shared__ int sh[256];
    const int t = threadIdx.x;
    const int i = blockIdx.x * 256 + t;
    sh[t] = deg[i];
    __syncthreads();
    for (int o = 1; o < 256; o <<= 1) {
        int add = (t >= o) ? sh[t - o] : 0;
        __syncthreads();
        sh[t] += add;
        __syncthreads();
    }
    incl[i] = sh[t];
    if (t == 255) bsum[blockIdx.x] = sh[255];
}
__global__ void scan2_k(const int* __restrict__ bsum, int* __restrict__ boff) {
    __shared__ int sh[256];
    const int t = threadIdx.x;
    int v = (t < 250) ? bsum[t] : 0;
    sh[t] = v;
    __syncthreads();
    for (int o = 1; o < 256; o <<= 1) {
        int add = (t >= o) ? sh[t - o] : 0;
        __syncthreads();
        sh[t] += add;
        __syncthreads();
    }
    if (t < 250) boff[t] = sh[t] - v;   // exclusive
}
__global__ void scan3_k(const int* __restrict__ incl, const int* __restrict__ boff,
                        int* __restrict__ rowptr, int* __restrict__ cursor_deg) {
    const int i = blockIdx.x * 256 + threadIdx.x;
    int total = incl[i] + boff[blockIdx.x];
    int excl  = total - cursor_deg[i];
    rowptr[i] = excl;
    cursor_deg[i] = excl;                 // becomes fill cursor
    if (i == NT - 1) rowptr[NT] = total;
}
__global__ void fill_k(const int* __restrict__ ei, int* __restrict__ cursor, int* __restrict__ srcs) {
    int e = blockIdx.x * 256 + threadIdx.x;
    if (e < ET) {
        int s_, d_;
        if (e < EG) { s_ = ei[e]; d_ = ei[EG + e]; }
        else        { s_ = e - EG; d_ = s_; }
        int p = atomicAdd(cursor + d_, 1);
        srcs[p] = s_;
    }
}

// ---------------- bf16 split-precision W fragments for MFMA GEMM ----------------
__global__ void build_gfrag_k(const float* __restrict__ src, const int ks, const int ns,
                              const int K, ushort* __restrict__ dhi, ushort* __restrict__ dlo,
                              const int total) {
    int id = blockIdx.x * 256 + threadIdx.x;
    if (id < total) {
        int j = id & 7, lane = (id >> 3) & 63;
        int f = id >> 9;
        int KT = K >> 5;
        int nt = f / KT, kt = f - nt * KT;
        int n = nt * 16 + (lane & 15);
        int k = kt * 32 + ((lane >> 4) << 3) + j;
        float v = src[(size_t)k * ks + (size_t)n * ns];
        ushort h = f2bf(v);
        dhi[id] = h;
        dlo[id] = f2bf(v - bf2f(h));
    }
}
__global__ void bias512_k(const float* __restrict__ bih, const float* __restrict__ bhh,
                          float* __restrict__ b512) {
    int i = blockIdx.x * 256 + threadIdx.x;
    if (i < 512) b512[i] = bih[i] + bhh[i];
}

// ---------------- MFMA GEMM: out[M x N] = x[M x K] @ W + bias, split bf16 hi/lo ----------------
// Full-line stores: 16 lanes (col) write 64B contiguous per quad — no write amplification.
template <int KT>
__global__ __launch_bounds__(256) void gemm_mf(
    const float* __restrict__ x, const ushort* __restrict__ bhi,
    const ushort* __restrict__ blo, const float* __restrict__ bias,
    float* __restrict__ out, const int ldout)
{
    constexpr int K = KT * 32;
    __shared__ __align__(16) ushort ahi_s[64 * 136];
    __shared__ __align__(16) ushort alo_s[64 * 136];
    const int t = threadIdx.x;
    const int w = t >> 6, lane = t & 63;
    const int quad = lane >> 4, col = lane & 15;
    const int row0 = blockIdx.x * 64;
    const int col0 = blockIdx.y * 128;

    {
        const int r  = t >> 2;
        const int kc = (t & 3) * (K / 4);
        const float* xr = x + (size_t)(row0 + r) * K + kc;
        ushort* dh = ahi_s + r * 136 + kc;
        ushort* dl = alo_s + r * 136 + kc;
#pragma unroll
        for (int k = 0; k < K / 4; k += 4) {
            float4 v = *(const float4*)(xr + k);
            ushort h0_ = f2bf(v.x), h1_ = f2bf(v.y), h2_ = f2bf(v.z), h3_ = f2bf(v.w);
            ushort l0_ = f2bf(v.x - bf2f(h0_)), l1_ = f2bf(v.y - bf2f(h1_));
            ushort l2_ = f2bf(v.z - bf2f(h2_)), l3_ = f2bf(v.w - bf2f(h3_));
            *(uint2*)(dh + k) = make_uint2((uint)h0_ | ((uint)h1_ << 16),
                                           (uint)h2_ | ((uint)h3_ << 16));
            *(uint2*)(dl + k) = make_uint2((uint)l0_ | ((uint)l1_ << 16),
                                           (uint)l2_ | ((uint)l3_ << 16));
        }
    }
    __syncthreads();

    short8 ah[KT], al[KT];
#pragma unroll
    for (int kt = 0; kt < KT; kt++) {
        const int off = (w * 16 + col) * 136 + kt * 32 + quad * 8;
        ah[kt] = *(const short8*)(ahi_s + off);
        al[kt] = *(const short8*)(alo_s + off);
    }

    f32x4 acc[8];
#pragma unroll
    for (int q = 0; q < 8; q++) acc[q] = (f32x4){0.f, 0.f, 0.f, 0.f};

#pragma unroll
    for (int q = 0; q < 8; q++) {
#pragma unroll
        for (int kt = 0; kt < KT; kt++) {
            const int f = ((((col0 >> 4) + q) * KT + kt) * 64 + lane) * 8;
            short8 bh = *(const short8*)(bhi + f);
            short8 bl = *(const short8*)(blo + f);
            acc[q] = __builtin_amdgcn_mfma_f32_16x16x32_bf16(ah[kt], bh, acc[q], 0, 0, 0);
            acc[q] = __builtin_amdgcn_mfma_f32_16x16x32_bf16(al[kt], bh, acc[q], 0, 0, 0);
            acc[q] = __builtin_amdgcn_mfma_f32_16x16x32_bf16(ah[kt], bl, acc[q], 0, 0, 0);
        }
    }

#pragma unroll
    for (int q = 0; q < 8; q++) {
        float bv = bias[col0 + q * 16 + col];
#pragma unroll
        for (int r = 0; r < 4; r++) {
            out[(size_t)(row0 + w * 16 + quad * 4 + r) * ldout + col0 + q * 16 + col]
                = acc[q][r] + bv;
        }
    }
}

// ---------------- fp32 GEMM (fallback path only) ----------------
template <int K>
__global__ __launch_bounds__(256) void gemm3(
    const float* __restrict__ x, const float* __restrict__ W,
    const float* __restrict__ b, float* __restrict__ out)
{
    __shared__ float Wsh[64 * 128];
    __shared__ float xT[64][132];
    const int t = threadIdx.x;
    const int row0 = blockIdx.x * 128;
    const int cg = t & 15;
    const int rg = t >> 4;
    float4 acc[8][2];
#pragma unroll
    for (int r = 0; r < 8; r++) {
        acc[r][0] = make_float4(0.f, 0.f, 0.f, 0.f);
        acc[r][1] = make_float4(0.f, 0.f, 0.f, 0.f);
    }
    for (int k0 = 0; k0 < K; k0 += 64) {
        for (int i = t * 4; i < 64 * 128; i += 1024)
            *(float4*)(Wsh + i) = *(const float4*)(W + (size_t)k0 * 128 + i);
        for (int i = t * 4; i < 128 * 64; i += 1024) {
            int r = i >> 6, k = i & 63;
            float4 v = *(const float4*)(x + (size_t)(row0 + r) * K + k0 + k);
            xT[k + 0][r] = v.x; xT[k + 1][r] = v.y;
            xT[k + 2][r] = v.z; xT[k + 3][r] = v.w;
        }
        __syncthreads();
#pragma unroll 2
        for (int k = 0; k < 64; k++) {
            float4 w0 = *(const float4*)(Wsh + k * 128 + cg * 8);
            float4 w1 = *(const float4*)(Wsh + k * 128 + cg * 8 + 4);
            float4 x0 = *(const float4*)(&xT[k][rg * 8]);
            float4 x1 = *(const float4*)(&xT[k][rg * 8 + 4]);
            float xv[8] = {x0.x, x0.y, x0.z, x0.w, x1.x, x1.y, x1.z, x1.w};
#pragma unroll
            for (int r = 0; r < 8; r++) {
                acc[r][0].x += xv[r] * w0.x; acc[r][0].y += xv[r] * w0.y;
                acc[r][0].z += xv[r] * w0.z; acc[r][0].w += xv[r] * w0.w;
                acc[r][1].x += xv[r] * w1.x; acc[r][1].y += xv[r] * w1.y;
                acc[r][1].z += xv[r] * w1.z; acc[r][1].w += xv[r] * w1.w;
            }
        }
        __syncthreads();
    }
    float4 bv0 = *(const float4*)(b + cg * 8);
    float4 bv1 = *(const float4*)(b + cg * 8 + 4);
#pragma unroll
    for (int r = 0; r < 8; r++) {
        float4 o0, o1;
        o0.x = acc[r][0].x + bv0.x; o0.y = acc[r][0].y + bv0.y;
        o0.z = acc[r][0].z + bv0.z; o0.w = acc[r][0].w + bv0.w;
        o1.x = acc[r][1].x + bv1.x; o1.y = acc[r][1].y + bv1.y;
        o1.z = acc[r][1].z + bv1.z; o1.w = acc[r][1].w + bv1.w;
        float* op = out + (size_t)(row0 + rg * 8 + r) * 128 + cg * 8;
        *(float4*)(op) = o0;
        *(float4*)(op + 4) = o1;
    }
}

// ---------------- fused GATv2: 2-way pipelined online softmax ----------------
__global__ __launch_bounds__(256) void gat_fused_k(
    const float* __restrict__ xl, const int* __restrict__ rowptr,
    const int* __restrict__ srcs, const float* __restrict__ att,
    const float* __restrict__ bias, float* __restrict__ out, const int do_relu)
{
    const int lane = threadIdx.x & 63;
    const int b = blockIdx.x;
    const int g = b & 7;
    const int j = b >> 3;
    const int jq = j / 250;
    const int jj = j - jq * 250;
    const int s = g + 8 * jq;
    const int n = s * NN + jj * 4 + (threadIdx.x >> 6);

    const float2 a = *(const float2*)(att + lane * 2);
    const float2 xd = *(const float2*)(xl + (size_t)n * 128 + lane * 2);
    const int i0 = rowptr[n], i1 = rowptr[n + 1];

    float m0 = -1e30f, d0 = 0.f, ax0 = 0.f, ay0 = 0.f;
    float m1 = -1e30f, d1 = 0.f, ax1 = 0.f, ay1 = 0.f;

    int i = i0;
    int sv0 = srcs[i];
    int sv1 = (i + 1 < i1) ? srcs[i + 1] : 0;
    while (i + 1 < i1) {
        const float2 xs0 = *(const float2*)(xl + (size_t)sv0 * 128 + lane * 2);
        const float2 xs1 = *(const float2*)(xl + (size_t)sv1 * 128 + lane * 2);
        sv0 = (i + 2 < i1) ? srcs[i + 2] : 0;
        sv1 = (i + 3 < i1) ? srcs[i + 3] : 0;

        float u0 = xs0.x + xd.x, v0 = xs0.y + xd.y;
        float u1 = xs1.x + xd.x, v1 = xs1.y + xd.y;
        u0 = (u0 > 0.f) ? u0 : 0.2f * u0;  v0 = (v0 > 0.f) ? v0 : 0.2f * v0;
        u1 = (u1 > 0.f) ? u1 : 0.2f * u1;  v1 = (v1 > 0.f) ? v1 : 0.2f * v1;
        float p0 = u0 * a.x + v0 * a.y;
        float p1 = u1 * a.x + v1 * a.y;
        p0 += __shfl_xor(p0, 1, 32);   p1 += __shfl_xor(p1, 1, 32);
        p0 += __shfl_xor(p0, 2, 32);   p1 += __shfl_xor(p1, 2, 32);
        p0 += __shfl_xor(p0, 4, 32);   p1 += __shfl_xor(p1, 4, 32);
        p0 += __shfl_xor(p0, 8, 32);   p1 += __shfl_xor(p1, 8, 32);
        p0 += __shfl_xor(p0, 16, 32);  p1 += __shfl_xor(p1, 16, 32);

        float mn0 = fmaxf(m0, p0),  mn1 = fmaxf(m1, p1);
        float sc0 = __expf(m0 - mn0), sc1 = __expf(m1 - mn1);
        float w0 = __expf(p0 - mn0),  w1 = __expf(p1 - mn1);
        d0 = d0 * sc0 + w0;             d1 = d1 * sc1 + w1;
        ax0 = ax0 * sc0 + w0 * xs0.x;   ax1 = ax1 * sc1 + w1 * xs1.x;
        ay0 = ay0 * sc0 + w0 * xs0.y;   ay1 = ay1 * sc1 + w1 * xs1.y;
        m0 = mn0;                       m1 = mn1;
        i += 2;
    }
    if (i < i1) {   // odd leftover -> set0
        const float2 xs0 = *(const float2*)(xl + (size_t)sv0 * 128 + lane * 2);
        float u0 = xs0.x + xd.x, v0 = xs0.y + xd.y;
        u0 = (u0 > 0.f) ? u0 : 0.2f * u0;  v0 = (v0 > 0.f) ? v0 : 0.2f * v0;
        float p0 = u0 * a.x + v0 * a.y;
        p0 += __shfl_xor(p0, 1, 32);
        p0 += __shfl_xor(p0, 2, 32);
        p0 += __shfl_xor(p0, 4, 32);
        p0 += __shfl_xor(p0, 8, 32);
        p0 += __shfl_xor(p0, 16, 32);
        float mn0 = fmaxf(m0, p0);
        float sc0 = __expf(m0 - mn0), w0 = __expf(p0 - mn0);
        d0 = d0 * sc0 + w0;
        ax0 = ax0 * sc0 + w0 * xs0.x;
        ay0 = ay0 * sc0 + w0 * xs0.y;
        m0 = mn0;
    }
    float mm = fmaxf(m0, m1);
    float s0 = __expf(m0 - mm), s1 = __expf(m1 - mm);
    float den = d0 * s0 + d1 * s1;
    float ax = ax0 * s0 + ax1 * s1;
    float ay = ay0 * s0 + ay1 * s1;

    float2 bv = *(const float2*)(bias + lane * 2);
    float inv = 1.f / den;
    float ox = ax * inv + bv.x, oy = ay * inv + bv.y;
    if (do_relu) { ox = fmaxf(ox, 0.f); oy = fmaxf(oy, 0.f); }
    *(float2*)(out + (size_t)n * 128 + lane * 2) = make_float2(ox, oy);
}

// ---------------- LSTM weight packing (fallback path) ----------------
__global__ void build_wq_k(const float* __restrict__ Wih, const float* __restrict__ Whh,
                           float4* __restrict__ WQa, float4* __restrict__ WQb) {
    int id = blockIdx.x * 256 + threadIdx.x;
    if (id < 64 * 256) {
        int kp = id >> 8, t = id & 255;
        int j1 = t, j2 = t + 256;
        WQa[id] = make_float4(Wih[(size_t)j1 * 128 + 2 * kp], Whh[(size_t)j1 * 128 + 2 * kp],
                              Wih[(size_t)j1 * 128 + 2 * kp + 1], Whh[(size_t)j1 * 128 + 2 * kp + 1]);
        WQb[id] = make_float4(Wih[(size_t)j2 * 128 + 2 * kp], Whh[(size_t)j2 * 128 + 2 * kp],
                              Wih[(size_t)j2 * 128 + 2 * kp + 1], Whh[(size_t)j2 * 128 + 2 * kp + 1]);
    }
}

// ---------------- bf16 B-fragment pack of Whh (LSTM MFMA) ----------------
__global__ void build_bfrag_k(const float* __restrict__ Whh, ushort* __restrict__ Bfrag) {
    int id = blockIdx.x * 256 + threadIdx.x;    // 65536 ids
    if (id < 65536) {
        int j = id & 7, lane = (id >> 3) & 63, kt = (id >> 9) & 3, tile = id >> 11;
        int gate = tile * 16 + (lane & 15);
        int k = kt * 32 + ((lane >> 4) << 3) + j;
        Bfrag[id] = f2bf(Whh[(size_t)gate * 128 + k]);
    }
}

// ---- fallback LSTM (round-3, small-ws only) ----
#define LSTM_GROUP(buf, gbase)                                                     \
    _Pragma("unroll")                                                              \
    for (int i_ = 0; i_ < 4; i_++) {                                               \
        const int kp_ = (gbase) * 4 + i_;                                          \
        const float4 qa_ = buf[i_];                                                \
        const float4 qb_ = buf[4 + i_];                                            \
        _Pragma("unroll")                                                          \
        for (int n_ = 0; n_ < 4; n_++) {                                           \
            const float sx0_ = rdlane(xr[n_].x, kp_);                              \
            const float sh0_ = rdlane(hr[n_].x, kp_);                              \
            const float sx1_ = rdlane(xr[n_].y, kp_);                              \
            const float sh1_ = rdlane(hr[n_].y, kp_);                              \
            acc1[n_] += sx0_ * qa_.x + sh0_ * qa_.y + sx1_ * qa_.z + sh1_ * qa_.w; \
            acc2[n_] += sx0_ * qb_.x + sh0_ * qb_.y + sx1_ * qb_.z + sh1_ * qb_.w; \
        }                                                                          \
    }

__global__ __launch_bounds__(256, 1) void lstm_k(
    float* __restrict__ mu, const float4* __restrict__ WQa, const float4* __restrict__ WQb,
    const float* __restrict__ bih, const float* __restrict__ bhh,
    const float* __restrict__ h0, const float* __restrict__ c0,
    float* __restrict__ hT, float* __restrict__ cT)
{
    const int t = threadIdx.x, lane = t & 63;
    const int n0 = blockIdx.x * 4;
    __shared__ float hsh[4][128];
    __shared__ float gsh[4][512];
    const float b1 = bih[t] + bhh[t];
    const float b2 = bih[t + 256] + bhh[t + 256];
    float creg[2];
#pragma unroll
    for (int q = 0; q < 2; q++) {
        int id = t + 256 * q;
        creg[q] = c0[(size_t)(n0 + (id >> 7)) * 128 + (id & 127)];
    }
    for (int i = t; i < 512; i += 256)
        hsh[i >> 7][i & 127] = h0[(size_t)(n0 + (i >> 7)) * 128 + (i & 127)];

    const float4* pA = WQa + t;
    const float4* pB = WQb + t;

    float2 xr[4], xnx[4];
#pragma unroll
    for (int n = 0; n < 4; n++)
        xr[n] = *(const float2*)(mu + (size_t)n0 * 128 + n * 128 + lane * 2);
    __syncthreads();

    for (int s = 0; s < SQ; s++) {
        float* xrow = mu + ((size_t)s * NN + n0) * 128;
        float2 hr[4];
#pragma unroll
        for (int n = 0; n < 4; n++) hr[n] = *(const float2*)(&hsh[n][lane * 2]);

        float4 bufA[8], bufB[8];
#pragma unroll
        for (int i = 0; i < 4; i++) { bufA[i] = pA[i * 256]; bufA[4 + i] = pB[i * 256]; }

        if (s + 1 < SQ) {
            const float* xrow2 = mu + ((size_t)(s + 1) * NN + n0) * 128;
#pragma unroll
            for (int n = 0; n < 4; n++) xnx[n] = *(const float2*)(xrow2 + n * 128 + lane * 2);
        }

        float acc1[4], acc2[4];
#pragma unroll
        for (int n = 0; n < 4; n++) { acc1[n] = b1; acc2[n] = b2; }

        for (int g = 0; g < 16; g += 2) {
#pragma unroll
            for (int i = 0; i < 4; i++) {
                bufB[i]     = pA[((g + 1) * 4 + i) * 256];
                bufB[4 + i] = pB[((g + 1) * 4 + i) * 256];
            }
            LSTM_GROUP(bufA, g)
            if (g < 14) {
#pragma unroll
                for (int i = 0; i < 4; i++) {
                    bufA[i]     = pA[((g + 2) * 4 + i) * 256];
                    bufA[4 + i] = pB[((g + 2) * 4 + i) * 256];
                }
            }
            LSTM_GROUP(bufB, g + 1)
        }

#pragma unroll
        for (int n = 0; n < 4; n++) { gsh[n][t] = acc1[n]; gsh[n][t + 256] = acc2[n]; }
        __syncthreads();
#pragma unroll
        for (int q = 0; q < 2; q++) {
            int id = t + 256 * q;
            int n = id >> 7, e = id & 127;
            float iv = gsh[n][e], fv = gsh[n][128 + e];
            float gv = gsh[n][256 + e], ov = gsh[n][384 + e];
            float c = sigm(fv) * creg[q] + sigm(iv) * tanh_f(gv);
            float h = sigm(ov) * tanh_f(c);
            creg[q] = c;
            hsh[n][e] = h;
            xrow[n * 128 + e] = h;
            if (s == SQ - 1) {
                hT[(size_t)(n0 + n) * 128 + e] = h;
                cT[(size_t)(n0 + n) * 128 + e] = c;
            }
        }
#pragma unroll
        for (int n = 0; n < 4; n++) xr[n] = xnx[n];
        __syncthreads();
    }
}

// ---------------- MFMA LSTM v4 (big-ws path) ----------------
// 63 blocks x 16 nodes, single barrier/step, ping-pong h buffers.
// xC (row-major) is consumed via cooperative LDS staging: each step the block's
// 32KB slab (16 nodes x 512 gates) is loaded with 8 coalesced float4/thread,
// prefetched one step ahead into a ping-pong LDS buffer (ds_write placed after
// the MFMA block so the vmcnt wait overlaps compute). Epilogue reads gates
// from LDS (4-way bank aliasing, ~290cyc/step — acceptable).
__global__ __launch_bounds__(256, 1) void lstm5_k(
    float* __restrict__ mu, const float* __restrict__ xC,
    const ushort* __restrict__ Bfrag,
    const float* __restrict__ h0, const float* __restrict__ c0,
    float* __restrict__ hT, float* __restrict__ cT)
{
    const int t = threadIdx.x;
    const int w = t >> 6, lane = t & 63;
    const int quad = lane >> 4, col = lane & 15;
    const int n0 = blockIdx.x * 16;
    const int c_ = w * 16 + col;                  // 0..63 channel-within-64

    __shared__ __align__(16) ushort hbuf[2][2][16 * 136];   // [pingpong][hi/lo]
    __shared__ __align__(16) float xcs[2][16 * 512];        // 2 x 32KB gate slabs

    // B fragments -> registers (constant all 64 steps)
    short8 bf[8][4];
#pragma unroll
    for (int q = 0; q < 8; q++)
#pragma unroll
        for (int kt = 0; kt < 4; kt++) {
            int tile = q * 4 + w;
            bf[q][kt] = *(const short8*)(Bfrag + (((tile * 4 + kt) * 64 + lane) << 3));
        }

    // init h into both buffers, c into regs
    for (int i = t; i < 2048; i += 256) {
        int node = i >> 7, e = i & 127;
        int gn = n0 + node;
        float v = (gn < NN) ? h0[(size_t)gn * 128 + e] : 0.f;
        ushort hh = f2bf(v), hl = f2bf(v - bf2f(hh));
        hbuf[0][0][node * 136 + e] = hh; hbuf[0][1][node * 136 + e] = hl;
        hbuf[1][0][node * 136 + e] = hh; hbuf[1][1][node * 136 + e] = hl;
    }
    float cst[8];
#pragma unroll
    for (int q = 0; q < 2; q++)
#pragma unroll
        for (int r = 0; r < 4; r++) {
            int gn = n0 + quad * 4 + r;
            cst[q * 4 + r] = (gn < NN) ? c0[(size_t)gn * 128 + (q * 64 + c_)] : 0.f;
        }

    // stage step-0 xC slab (rows n0..n0+15; rows >= NN read harmless garbage)
    {
        const float* src = xC + (size_t)n0 * 512;
        for (int i = t; i < 2048; i += 256)
            *(float4*)&xcs[0][i * 4] = *(const float4*)(src + (size_t)i * 4);
    }
    __syncthreads();

    int p = 0, bx = 0;
    for (int s = 0; s < SQ; s++) {
        // 1. issue next step's global loads (regs) — overlap with MFMA below
        float4 pre[8];
        if (s + 1 < SQ) {
            const float* src = xC + ((size_t)(s + 1) * NN + n0) * 512;
#pragma unroll
            for (int i = 0; i < 8; i++)
                pre[i] = *(const float4*)(src + (size_t)(t + i * 256) * 4);
        }

        // 2. A fragments from current h buffer
        short8 ahi[4], alo[4];
#pragma unroll
        for (int kt = 0; kt < 4; kt++) {
            ahi[kt] = *(const short8*)(&hbuf[p][0][col * 136 + kt * 32 + quad * 8]);
            alo[kt] = *(const short8*)(&hbuf[p][1][col * 136 + kt * 32 + quad * 8]);
        }

        // 3. MFMA block
        f32x4 acc[8];
#pragma unroll
        for (int q = 0; q < 8; q++) acc[q] = (f32x4){0.f, 0.f, 0.f, 0.f};
#pragma unroll
        for (int kt = 0; kt < 4; kt++) {
#pragma unroll
            for (int q = 0; q < 8; q++) {
                acc[q] = __builtin_amdgcn_mfma_f32_16x16x32_bf16(ahi[kt], bf[q][kt], acc[q], 0, 0, 0);
                acc[q] = __builtin_amdgcn_mfma_f32_16x16x32_bf16(alo[kt], bf[q][kt], acc[q], 0, 0, 0);
            }
        }

        // 4. commit prefetched slab to the other xc buffer
        if (s + 1 < SQ) {
#pragma unroll
            for (int i = 0; i < 8; i++)
                *(float4*)&xcs[bx ^ 1][(t + i * 256) * 4] = pre[i];
        }

        // 5. epilogue: gates = acc + xcs[bx]; h -> other h buffer
        float* mus = mu + (size_t)s * (NN * 128);
        const float* xg = xcs[bx];
        const int pn = p ^ 1;
#pragma unroll
        for (int r = 0; r < 4; r++) {
            const int node = quad * 4 + r;
            const int gn = n0 + node;
            const int base = node * 512;
            // q = 0 cell (channel c_)
            {
                float iv = acc[0][r] + xg[base + c_];
                float fv = acc[2][r] + xg[base + 128 + c_];
                float gv = acc[4][r] + xg[base + 256 + c_];
                float ov = acc[6][r] + xg[base + 384 + c_];
                float c = sigm(fv) * cst[r] + sigm(iv) * tanh2(gv);
                float h = sigm(ov) * tanh2(c);
                cst[r] = c;
                ushort hh = f2bf(h);
                hbuf[pn][0][node * 136 + c_] = hh;
                hbuf[pn][1][node * 136 + c_] = f2bf(h - bf2f(hh));
                if (gn < NN) {
                    mus[(size_t)gn * 128 + c_] = h;
                    if (s == SQ - 1) {
                        hT[(size_t)gn * 128 + c_] = h;
                        cT[(size_t)gn * 128 + c_] = c;
                    }
                }
            }
            // q = 1 cell (channel 64 + c_)
            {
                const int e = 64 + c_;
                float iv = acc[1][r] + xg[base + e];
                float fv = acc[3][r] + xg[base + 128 + e];
                float gv = acc[5][r] + xg[base + 256 + e];
                float ov = acc[7][r] + xg[base + 384 + e];
                float c = sigm(fv) * cst[4 + r] + sigm(iv) * tanh2(gv);
                float h = sigm(ov) * tanh2(c);
                cst[4 + r] = c;
                ushort hh = f2bf(h);
                hbuf[pn][0][node * 136 + e] = hh;
                hbuf[pn][1][node * 136 + e] = f2bf(h - bf2f(hh));
                if (gn < NN) {
                    mus[(size_t)gn * 128 + e] = h;
                    if (s == SQ - 1) {
                        hT[(size_t)gn * 128 + e] = h;
                        cT[(size_t)gn * 128 + e] = c;
                    }
                }
            }
        }
        p = pn;
        bx ^= 1;
        __syncthreads();
    }
}

// ---------------- head: meanpool -> gs -> A[s] (r7 version — proven) ----------------
__global__ __launch_bounds__(256) void meanpool_gs_k(
    const float* __restrict__ mu, const float* __restrict__ W6,
    const float* __restrict__ b6, const float* __restrict__ w5,
    float* __restrict__ A)
{
    const int s = blockIdx.x, t = threadIdx.x;
    const int ch = t & 127, half = t >> 7;
    __shared__ float mp[128];
    __shared__ float red[256];
    float acc = 0.f;
    for (int n = half * 500; n < (half + 1) * 500; n++)
        acc += mu[((size_t)s * NN + n) * 128 + ch];
    red[t] = acc;
    __syncthreads();
    if (t < 128) mp[t] = (red[t] + red[t + 128]) * 0.001f;
    __syncthreads();
    float g = 0.f;
    if (t < 128) {
        g = b6[t];
        for (int k = 0; k < 128; k++) g += mp[k] * W6[(size_t)k * 128 + t];
        g = fmaxf(g, 0.f) * w5[t];
    }
    red[t] = g;
    __syncthreads();
    for (int o = 128; o > 0; o >>= 1) {
        if (t < o) red[t] += red[t + o];
        __syncthreads();
    }
    if (t == 0) A[s] = red[0];
}

// ---------------- head: logit2[row] ----------------
__global__ __launch_bounds__(256) void rowdot_k(
    const float* __restrict__ la, const float* __restrict__ w5,
    const float* __restrict__ b5, const float* __restrict__ A,
    float* __restrict__ out)
{
    const int lane = threadIdx.x & 63;
    const int row = blockIdx.x * 4 + (threadIdx.x >> 6);
    float2 v = *(const float2*)(la + (size_t)row * 128 + lane * 2);
    float2 w = *(const float2*)(w5 + 128 + lane * 2);
    float x = fmaxf(v.x, 0.f) * w.x + fmaxf(v.y, 0.f) * w.y;
#pragma unroll
    for (int o = 32; o; o >>= 1) x += __shfl_down(x, o);
    if (lane == 0) out[row] = x + A[row / NN] + b5[0];
}

// ---------------- masked softmax per sequence step ----------------
__device__ __forceinline__ bool reach_at(const void* reach, int mode, int idx) {
    if (mode == 0) return ((const int*)reach)[idx] != 0;
    if (mode == 1) return ((const unsigned char*)reach)[idx] != 0;
    return ((const float*)reach)[idx] != 0.f;
}
__global__ __launch_bounds__(256) void softmax_k(
    const float* __restrict__ lg, const void* __restrict__ reach,
    const int* __restrict__ mode, float* __restrict__ prob)
{
    const int s = blockIdx.x, t = threadIdx.x;
    const int m = *mode;
    __shared__ float red[256];
    float mx = -1e30f;
    for (int i = t; i < NN; i += 256) {
        int idx = s * NN + i;
        if (reach_at(reach, m, idx)) mx = fmaxf(mx, lg[idx]);
    }
    red[t] = mx;
    __syncthreads();
    for (int o = 128; o; o >>= 1) {
        if (t < o) red[t] = fmaxf(red[t], red[t + o]);
        __syncthreads();
    }
    mx = red[0];
    __syncthreads();
    float sum = 0.f;
    for (int i = t; i < NN; i += 256) {
        int idx = s * NN + i;
        float v = reach_at(reach, m, idx) ? __expf(lg[idx] - mx) : 0.f;
        prob[idx] = v;
        sum += v;
    }
    red[t] = sum;
    __syncthreads();
    for (int o = 128; o; o >>= 1) {
        if (t < o) red[t] += red[t + o];
        __syncthreads();
    }
    float inv = 1.f / red[0];
    for (int i = t; i < NN; i += 256) prob[s * NN + i] *= inv;
}

// ---------------- driver ----------------
extern "C" void kernel_launch(void* const* d_in, const int* in_sizes, int n_in,
                              void* d_out, int out_size, void* d_ws, size_t ws_size,
                              hipStream_t stream) {
    const float* nfm   = (const float*)d_in[0];
    const int*   ei    = (const int*)d_in[1];
    const void*  reach = d_in[2];
    const float* h0    = (const float*)d_in[3];
    const float* c0    = (const float*)d_in[4];
    const float* W1    = (const float*)d_in[5];
    const float* b1    = (const float*)d_in[6];
    const float* att1  = (const float*)d_in[7];
    const float* bias1 = (const float*)d_in[8];
    const float* Wl    = (const float*)d_in[9];
    const float* bl    = (const float*)d_in[10];
    const float* attl  = (const float*)d_in[11];
    const float* biasl = (const float*)d_in[12];
    const float* Wih   = (const float*)d_in[13];
    const float* Whh   = (const float*)d_in[14];
    const float* bih   = (const float*)d_in[15];
    const float* bhh   = (const float*)d_in[16];
    const float* W6    = (const float*)d_in[17];
    const float* b6    = (const float*)d_in[18];
    const float* W7    = (const float*)d_in[19];
    const float* b7    = (const float*)d_in[20];
    const float* w5    = (const float*)d_in[21];
    const float* b5    = (const float*)d_in[22];

    char* ws = (char*)d_ws;
    const bool bigws = (ws_size >= WS2_NEED);

    float*  xA     = (float*)(ws + WS_XA);
    float*  xB     = (float*)(ws + WS_XB);
    int*    rowptr = (int*)(ws + WS_ROWPTR);
    int*    cursor = (int*)(ws + WS_CURSOR);
    int*    srcs   = (int*)(ws + WS_SRCS);
    int*    incl   = (int*)(ws + WS_INCL);
    int*    bsum   = (int*)(ws + WS_BSUM);
    int*    boff   = (int*)(ws + WS_BOFF);
    int*    modep  = bigws ? (int*)(ws + WS2_MODE)     : (int*)(ws + WS_MODE);
    float*  As     = bigws ? (float*)(ws + WS2_AS)     : (float*)(ws + WS_AS);
    float*  logit2 = bigws ? (float*)(ws + WS2_LOGIT2) : (float*)(ws + WS_LOGIT2);
    // big-ws extras
    float*  xC     = (float*)(ws + WS2_XC);
    ushort* Bfrag  = (ushort*)(ws + WS2_BFRAG);
    ushort* ghi    = (ushort*)(ws + WS2_GHI);
    ushort* glo    = (ushort*)(ws + WS2_GLO);
    float*  b512   = (float*)(ws + WS2_B512);
    // fallback extras
    float4* WQa    = (float4*)(ws + WS_WQA);
    float4* WQb    = (float4*)(ws + WS_WQB);

    float* prob = (float*)d_out;
    float* hT   = (float*)d_out + 64000;
    float* cT   = (float*)d_out + 192000;

    // setup
    detect_mode_k<<<1, 256, 0, stream>>>((const unsigned char*)reach, modep);
    zero_ints_k<<<250, 256, 0, stream>>>(cursor, NT);
    hist_k<<<2250, 256, 0, stream>>>(ei, cursor);
    scan1_k<<<250, 256, 0, stream>>>(cursor, incl, bsum);
    scan2_k<<<1, 256, 0, stream>>>(bsum, boff);
    scan3_k<<<250, 256, 0, stream>>>(incl, boff, rowptr, cursor);
    fill_k<<<2250, 256, 0, stream>>>(ei, cursor, srcs);
    if (bigws) {
        build_bfrag_k<<<256, 256, 0, stream>>>(Whh, Bfrag);
        bias512_k<<<2, 256, 0, stream>>>(bih, bhh, b512);
        build_gfrag_k<<<32, 256, 0, stream>>>(W1, 128, 1, 64, ghi + G_W1, glo + G_W1, 8192);
        for (int i = 0; i < 4; i++)
            build_gfrag_k<<<64, 256, 0, stream>>>(Wl + (size_t)i * 16384, 128, 1, 128,
                                                  ghi + G_WL + i * 16384, glo + G_WL + i * 16384, 16384);
        build_gfrag_k<<<256, 256, 0, stream>>>(Wih, 1, 128, 128, ghi + G_PROJ, glo + G_PROJ, 65536);
        build_gfrag_k<<<64, 256, 0, stream>>>(W7, 128, 1, 128, ghi + G_W7, glo + G_W7, 16384);
    } else {
        build_wq_k<<<64, 256, 0, stream>>>(Wih, Whh, WQa, WQb);
    }

    // 5 GATv2 layers: gemm (x->xB), fused logits+softmax+aggregate (xB->xA)
    for (int l = 0; l < 5; l++) {
        if (bigws) {
            if (l == 0)
                gemm_mf<2><<<dim3(1000, 1), 256, 0, stream>>>(nfm, ghi + G_W1, glo + G_W1, b1, xB, 128);
            else
                gemm_mf<4><<<dim3(1000, 1), 256, 0, stream>>>(xA, ghi + G_WL + (l - 1) * 16384,
                                                              glo + G_WL + (l - 1) * 16384,
                                                              bl + (l - 1) * 128, xB, 128);
        } else {
            if (l == 0)
                gemm3<64><<<500, 256, 0, stream>>>(nfm, W1, b1, xB);
            else
                gemm3<128><<<500, 256, 0, stream>>>(xA, Wl + (size_t)(l - 1) * 128 * 128,
                                                    bl + (l - 1) * 128, xB);
        }
        const float* att  = (l == 0) ? att1  : attl  + (l - 1) * 128;
        const float* bias = (l == 0) ? bias1 : biasl + (l - 1) * 128;
        gat_fused_k<<<16000, 256, 0, stream>>>(xB, rowptr, srcs, att, bias, xA,
                                               (l < 4) ? 1 : 0);
    }

    // LSTM
    if (bigws) {
        // xC = mu @ Wih^T + (bih+bhh), row-major (full-line writes, no amplification)
        gemm_mf<4><<<dim3(1000, 4), 256, 0, stream>>>(xA, ghi + G_PROJ, glo + G_PROJ, b512, xC, 512);
        lstm5_k<<<63, 256, 0, stream>>>(xA, xC, Bfrag, h0, c0, hT, cT);
    } else {
        lstm_k<<<250, 256, 0, stream>>>(xA, WQa, WQb, bih, bhh, h0, c0, hT, cT);
    }

    // head
    meanpool_gs_k<<<64, 256, 0, stream>>>(xA, W6, b6, w5, As);
    if (bigws)
        gemm_mf<4><<<dim3(1000, 1), 256, 0, stream>>>(xA, ghi + G_W7, glo + G_W7, b7, xB, 128);
    else
        gemm3<128><<<500, 256, 0, stream>>>(xA, W7, b7, xB);
    rowdot_k<<<16000, 256, 0, stream>>>(xB, w5, b5, As, logit2);
    softmax_k<<<64, 256, 0, stream>>>(logit2, reach, modep, prob);
}

// Round 10
// 832.099 us; speedup vs baseline: 1.1508x; 1.1146x over previous
//
#include <hip/hip_runtime.h>
#include <hip/hip_bf16.h>

// ---------------- problem constants ----------------
#define SQ   64        // seq len
#define NN   1000      // nodes per graph
#define NT   64000     // total nodes
#define EE   128       // emb dim
#define EG   512000    // graph edges (no self loops)
#define ET   576000    // edges + self loops

// ---------------- workspace layout (bytes) ----------------
// common / fallback region (<71 MB)
#define WS_XA      0ull          // 32,768,000  float[NT*128]  x ping (mu lives here)
#define WS_XB      33000000ull   // 32,768,000  float[NT*128]  x pong (xl / la)
#define WS_ROWPTR  66000000ull   // 256,004     int[NT+1]
#define WS_CURSOR  66300000ull   // 256,000     int[NT]
#define WS_SRCS    66600000ull   // 2,304,000   int[ET]  (src node id, dst-grouped)
#define WS_INCL    69000000ull   // 256,000     int[NT]
#define WS_BSUM    69300000ull   // 1,024       int[250]
#define WS_BOFF    69302048ull   // 1,024       int[250]
#define WS_MODE    69304096ull   // 4           int
#define WS_WQA     70000000ull   // 262,144     float4[64*256]  (fallback LSTM)
#define WS_WQB     70262144ull   // 262,144     float4[64*256]  (fallback LSTM)
#define WS_AS      70600000ull   // 256         float[64]
#define WS_LOGIT2  70700000ull   // 256,000     float[NT]
// big-ws region: xC aliases xB + CSR (disjoint lifetimes)
#define WS2_XC     33000000ull   // 131,072,000 float[NT*512]  gate preacts (row-major)
#define WS2_BFRAG  164100000ull  // 131,072     ushort bf16 Whh B-fragments (LSTM)
#define WS2_GHI    164300000ull  // 311,296     ushort GEMM W fragments (hi)
#define WS2_GLO    164650000ull  // 311,296     ushort GEMM W fragments (lo)
#define WS2_B512   165000000ull  // 2,048       float[512]     bih+bhh
#define WS2_MODE   165010000ull  // 4
#define WS2_AS     165020000ull  // 256
#define WS2_LOGIT2 165100000ull  // 256,000
#define WS2_NEED   165360000ull
// GEMM fragment sub-offsets (ushort elements within GHI/GLO)
#define G_W1    0        // 64x128  -> 8192
#define G_WL    8192     // 4 x 128x128 -> 16384 each
#define G_PROJ  73728    // 128x512 -> 65536
#define G_W7    139264   // 128x128 -> 16384

typedef __attribute__((ext_vector_type(8))) short short8;   // 8 bf16 (4 VGPRs)
typedef __attribute__((ext_vector_type(4))) float f32x4;

// ---------------- helpers ----------------
__device__ __forceinline__ float rdlane(float v, int l) {
    return __int_as_float(__builtin_amdgcn_readlane(__float_as_int(v), l));
}
__device__ __forceinline__ float sigm(float x) { return 1.0f / (1.0f + __expf(-x)); }
__device__ __forceinline__ float tanh_f(float x) {
    x = fminf(fmaxf(x, -30.0f), 30.0f);
    float e = __expf(2.0f * x);
    return (e - 1.0f) / (e + 1.0f);
}
__device__ __forceinline__ float tanh2(float x) {   // 2*sigmoid(2x)-1, inf-safe
    return 2.0f / (1.0f + __expf(-2.0f * x)) - 1.0f;
}
__device__ __forceinline__ ushort f2bf(float x) {   // round-to-nearest-even bf16
    unsigned u = __float_as_uint(x);
    unsigned r = (u + 0x7FFFu + ((u >> 16) & 1u)) >> 16;
    return (ushort)r;
}
__device__ __forceinline__ float bf2f(ushort h) {
    return __uint_as_float(((unsigned)h) << 16);
}

// ---------------- reachable dtype detection ----------------
__global__ void detect_mode_k(const unsigned char* __restrict__ p, int* __restrict__ mode) {
    __shared__ int f0, f3;
    const int t = threadIdx.x;
    if (t == 0) { f0 = 0; f3 = 0; }
    __syncthreads();
    int l0 = 0, l3 = 0;
    for (int i = t; i < 16000; i += 256) {
        if (p[4 * i])     l0 = 1;
        if (p[4 * i + 3]) l3 = 1;
    }
    if (l0) atomicOr(&f0, 1);
    if (l3) atomicOr(&f3, 1);
    __syncthreads();
    if (t == 0) {
        int m;
        if (f0 && f3)      m = 1;  // bool bytes
        else if (f0)       m = 0;  // int32
        else               m = 2;  // float32
        *mode = m;
    }
}

// ---------------- CSR construction (dst-grouped src list; built once) ----------------
__global__ void zero_ints_k(int* __restrict__ p, int n) {
    int i = blockIdx.x * 256 + threadIdx.x;
    if (i < n) p[i] = 0;
}
__global__ void hist_k(const int* __restrict__ ei, int* __restrict__ deg) {
    int e = blockIdx.x * 256 + threadIdx.x;
    if (e < ET) {
        int d = (e < EG) ? ei[EG + e] : (e - EG);
        atomicAdd(deg + d, 1);
    }
}
__global__ void scan1_k(const int* __restrict__ deg, int* __restrict__ incl, int* __restrict__ bsum) {
    __shared__ int sh[256];
    const int t = threadIdx.x;
    const int i = blockIdx.x * 256 + t;
    sh[t] = deg[i];
    __syncthreads();
    for (int o = 1; o < 256; o <<= 1) {
        int add = (t >= o) ? sh[t - o] : 0;
        __syncthreads();
        sh[t] += add;
        __syncthreads();
    }
    incl[i] = sh[t];
    if (t == 255) bsum[blockIdx.x] = sh[255];
}
__global__ void scan2_k(const int* __restrict__ bsum, int* __restrict__ boff) {
    __shared__ int sh[256];
    const int t = threadIdx.x;
    int v = (t < 250) ? bsum[t] : 0;
    sh[t] = v;
    __syncthreads();
    for (int o = 1; o < 256; o <<= 1) {
        int add = (t >= o) ? sh[t - o] : 0;
        __syncthreads();
        sh[t] += add;
        __syncthreads();
    }
    if (t < 250) boff[t] = sh[t] - v;   // exclusive
}
__global__ void scan3_k(const int* __restrict__ incl, const int* __restrict__ boff,
                        int* __restrict__ rowptr, int* __restrict__ cursor_deg) {
    const int i = blockIdx.x * 256 + threadIdx.x;
    int total = incl[i] + boff[blockIdx.x];
    int excl  = total - cursor_deg[i];
    rowptr[i] = excl;
    cursor_deg[i] = excl;                 // becomes fill cursor
    if (i == NT - 1) rowptr[NT] = total;
}
__global__ void fill_k(const int* __restrict__ ei, int* __restrict__ cursor, int* __restrict__ srcs) {
    int e = blockIdx.x * 256 + threadIdx.x;
    if (e < ET) {
        int s_, d_;
        if (e < EG) { s_ = ei[e]; d_ = ei[EG + e]; }
        else        { s_ = e - EG; d_ = s_; }
        int p = atomicAdd(cursor + d_, 1);
        srcs[p] = s_;
    }
}

// ---------------- bf16 split-precision W fragments for MFMA GEMM ----------------
__global__ void build_gfrag_k(const float* __restrict__ src, const int ks, const int ns,
                              const int K, ushort* __restrict__ dhi, ushort* __restrict__ dlo,
                              const int total) {
    int id = blockIdx.x * 256 + threadIdx.x;
    if (id < total) {
        int j = id & 7, lane = (id >> 3) & 63;
        int f = id >> 9;
        int KT = K >> 5;
        int nt = f / KT, kt = f - nt * KT;
        int n = nt * 16 + (lane & 15);
        int k = kt * 32 + ((lane >> 4) << 3) + j;
        float v = src[(size_t)k * ks + (size_t)n * ns];
        ushort h = f2bf(v);
        dhi[id] = h;
        dlo[id] = f2bf(v - bf2f(h));
    }
}
__global__ void bias512_k(const float* __restrict__ bih, const float* __restrict__ bhh,
                          float* __restrict__ b512) {
    int i = blockIdx.x * 256 + threadIdx.x;
    if (i < 512) b512[i] = bih[i] + bhh[i];
}

// ---------------- MFMA GEMM: out[M x N] = x[M x K] @ W + bias, split bf16 hi/lo ----------------
template <int KT>
__global__ __launch_bounds__(256) void gemm_mf(
    const float* __restrict__ x, const ushort* __restrict__ bhi,
    const ushort* __restrict__ blo, const float* __restrict__ bias,
    float* __restrict__ out, const int ldout)
{
    constexpr int K = KT * 32;
    __shared__ __align__(16) ushort ahi_s[64 * 136];
    __shared__ __align__(16) ushort alo_s[64 * 136];
    const int t = threadIdx.x;
    const int w = t >> 6, lane = t & 63;
    const int quad = lane >> 4, col = lane & 15;
    const int row0 = blockIdx.x * 64;
    const int col0 = blockIdx.y * 128;

    {
        const int r  = t >> 2;
        const int kc = (t & 3) * (K / 4);
        const float* xr = x + (size_t)(row0 + r) * K + kc;
        ushort* dh = ahi_s + r * 136 + kc;
        ushort* dl = alo_s + r * 136 + kc;
#pragma unroll
        for (int k = 0; k < K / 4; k += 4) {
            float4 v = *(const float4*)(xr + k);
            ushort h0_ = f2bf(v.x), h1_ = f2bf(v.y), h2_ = f2bf(v.z), h3_ = f2bf(v.w);
            ushort l0_ = f2bf(v.x - bf2f(h0_)), l1_ = f2bf(v.y - bf2f(h1_));
            ushort l2_ = f2bf(v.z - bf2f(h2_)), l3_ = f2bf(v.w - bf2f(h3_));
            *(uint2*)(dh + k) = make_uint2((uint)h0_ | ((uint)h1_ << 16),
                                           (uint)h2_ | ((uint)h3_ << 16));
            *(uint2*)(dl + k) = make_uint2((uint)l0_ | ((uint)l1_ << 16),
                                           (uint)l2_ | ((uint)l3_ << 16));
        }
    }
    __syncthreads();

    short8 ah[KT], al[KT];
#pragma unroll
    for (int kt = 0; kt < KT; kt++) {
        const int off = (w * 16 + col) * 136 + kt * 32 + quad * 8;
        ah[kt] = *(const short8*)(ahi_s + off);
        al[kt] = *(const short8*)(alo_s + off);
    }

    f32x4 acc[8];
#pragma unroll
    for (int q = 0; q < 8; q++) acc[q] = (f32x4){0.f, 0.f, 0.f, 0.f};

#pragma unroll
    for (int q = 0; q < 8; q++) {
#pragma unroll
        for (int kt = 0; kt < KT; kt++) {
            const int f = ((((col0 >> 4) + q) * KT + kt) * 64 + lane) * 8;
            short8 bh = *(const short8*)(bhi + f);
            short8 bl = *(const short8*)(blo + f);
            acc[q] = __builtin_amdgcn_mfma_f32_16x16x32_bf16(ah[kt], bh, acc[q], 0, 0, 0);
            acc[q] = __builtin_amdgcn_mfma_f32_16x16x32_bf16(al[kt], bh, acc[q], 0, 0, 0);
            acc[q] = __builtin_amdgcn_mfma_f32_16x16x32_bf16(ah[kt], bl, acc[q], 0, 0, 0);
        }
    }

#pragma unroll
    for (int q = 0; q < 8; q++) {
        float bv = bias[col0 + q * 16 + col];
#pragma unroll
        for (int r = 0; r < 4; r++) {
            out[(size_t)(row0 + w * 16 + quad * 4 + r) * ldout + col0 + q * 16 + col]
                = acc[q][r] + bv;
        }
    }
}

// ---------------- fp32 GEMM (fallback path only) ----------------
template <int K>
__global__ __launch_bounds__(256) void gemm3(
    const float* __restrict__ x, const float* __restrict__ W,
    const float* __restrict__ b, float* __restrict__ out)
{
    __shared__ float Wsh[64 * 128];
    __shared__ float xT[64][132];
    const int t = threadIdx.x;
    const int row0 = blockIdx.x * 128;
    const int cg = t & 15;
    const int rg = t >> 4;
    float4 acc[8][2];
#pragma unroll
    for (int r = 0; r < 8; r++) {
        acc[r][0] = make_float4(0.f, 0.f, 0.f, 0.f);
        acc[r][1] = make_float4(0.f, 0.f, 0.f, 0.f);
    }
    for (int k0 = 0; k0 < K; k0 += 64) {
        for (int i = t * 4; i < 64 * 128; i += 1024)
            *(float4*)(Wsh + i) = *(const float4*)(W + (size_t)k0 * 128 + i);
        for (int i = t * 4; i < 128 * 64; i += 1024) {
            int r = i >> 6, k = i & 63;
            float4 v = *(const float4*)(x + (size_t)(row0 + r) * K + k0 + k);
            xT[k + 0][r] = v.x; xT[k + 1][r] = v.y;
            xT[k + 2][r] = v.z; xT[k + 3][r] = v.w;
        }
        __syncthreads();
#pragma unroll 2
        for (int k = 0; k < 64; k++) {
            float4 w0 = *(const float4*)(Wsh + k * 128 + cg * 8);
            float4 w1 = *(const float4*)(Wsh + k * 128 + cg * 8 + 4);
            float4 x0 = *(const float4*)(&xT[k][rg * 8]);
            float4 x1 = *(const float4*)(&xT[k][rg * 8 + 4]);
            float xv[8] = {x0.x, x0.y, x0.z, x0.w, x1.x, x1.y, x1.z, x1.w};
#pragma unroll
            for (int r = 0; r < 8; r++) {
                acc[r][0].x += xv[r] * w0.x; acc[r][0].y += xv[r] * w0.y;
                acc[r][0].z += xv[r] * w0.z; acc[r][0].w += xv[r] * w0.w;
                acc[r][1].x += xv[r] * w1.x; acc[r][1].y += xv[r] * w1.y;
                acc[r][1].z += xv[r] * w1.z; acc[r][1].w += xv[r] * w1.w;
            }
        }
        __syncthreads();
    }
    float4 bv0 = *(const float4*)(b + cg * 8);
    float4 bv1 = *(const float4*)(b + cg * 8 + 4);
#pragma unroll
    for (int r = 0; r < 8; r++) {
        float4 o0, o1;
        o0.x = acc[r][0].x + bv0.x; o0.y = acc[r][0].y + bv0.y;
        o0.z = acc[r][0].z + bv0.z; o0.w = acc[r][0].w + bv0.w;
        o1.x = acc[r][1].x + bv1.x; o1.y = acc[r][1].y + bv1.y;
        o1.z = acc[r][1].z + bv1.z; o1.w = acc[r][1].w + bv1.w;
        float* op = out + (size_t)(row0 + rg * 8 + r) * 128 + cg * 8;
        *(float4*)(op) = o0;
        *(float4*)(op + 4) = o1;
    }
}

// ---------------- fused GATv2: 2-way pipelined online softmax ----------------
__global__ __launch_bounds__(256) void gat_fused_k(
    const float* __restrict__ xl, const int* __restrict__ rowptr,
    const int* __restrict__ srcs, const float* __restrict__ att,
    const float* __restrict__ bias, float* __restrict__ out, const int do_relu)
{
    const int lane = threadIdx.x & 63;
    const int b = blockIdx.x;
    const int g = b & 7;
    const int j = b >> 3;
    const int jq = j / 250;
    const int jj = j - jq * 250;
    const int s = g + 8 * jq;
    const int n = s * NN + jj * 4 + (threadIdx.x >> 6);

    const float2 a = *(const float2*)(att + lane * 2);
    const float2 xd = *(const float2*)(xl + (size_t)n * 128 + lane * 2);
    const int i0 = rowptr[n], i1 = rowptr[n + 1];

    float m0 = -1e30f, d0 = 0.f, ax0 = 0.f, ay0 = 0.f;
    float m1 = -1e30f, d1 = 0.f, ax1 = 0.f, ay1 = 0.f;

    int i = i0;
    int sv0 = srcs[i];
    int sv1 = (i + 1 < i1) ? srcs[i + 1] : 0;
    while (i + 1 < i1) {
        const float2 xs0 = *(const float2*)(xl + (size_t)sv0 * 128 + lane * 2);
        const float2 xs1 = *(const float2*)(xl + (size_t)sv1 * 128 + lane * 2);
        sv0 = (i + 2 < i1) ? srcs[i + 2] : 0;
        sv1 = (i + 3 < i1) ? srcs[i + 3] : 0;

        float u0 = xs0.x + xd.x, v0 = xs0.y + xd.y;
        float u1 = xs1.x + xd.x, v1 = xs1.y + xd.y;
        u0 = (u0 > 0.f) ? u0 : 0.2f * u0;  v0 = (v0 > 0.f) ? v0 : 0.2f * v0;
        u1 = (u1 > 0.f) ? u1 : 0.2f * u1;  v1 = (v1 > 0.f) ? v1 : 0.2f * v1;
        float p0 = u0 * a.x + v0 * a.y;
        float p1 = u1 * a.x + v1 * a.y;
        p0 += __shfl_xor(p0, 1, 32);   p1 += __shfl_xor(p1, 1, 32);
        p0 += __shfl_xor(p0, 2, 32);   p1 += __shfl_xor(p1, 2, 32);
        p0 += __shfl_xor(p0, 4, 32);   p1 += __shfl_xor(p1, 4, 32);
        p0 += __shfl_xor(p0, 8, 32);   p1 += __shfl_xor(p1, 8, 32);
        p0 += __shfl_xor(p0, 16, 32);  p1 += __shfl_xor(p1, 16, 32);

        float mn0 = fmaxf(m0, p0),  mn1 = fmaxf(m1, p1);
        float sc0 = __expf(m0 - mn0), sc1 = __expf(m1 - mn1);
        float w0 = __expf(p0 - mn0),  w1 = __expf(p1 - mn1);
        d0 = d0 * sc0 + w0;             d1 = d1 * sc1 + w1;
        ax0 = ax0 * sc0 + w0 * xs0.x;   ax1 = ax1 * sc1 + w1 * xs1.x;
        ay0 = ay0 * sc0 + w0 * xs0.y;   ay1 = ay1 * sc1 + w1 * xs1.y;
        m0 = mn0;                       m1 = mn1;
        i += 2;
    }
    if (i < i1) {   // odd leftover -> set0
        const float2 xs0 = *(const float2*)(xl + (size_t)sv0 * 128 + lane * 2);
        float u0 = xs0.x + xd.x, v0 = xs0.y + xd.y;
        u0 = (u0 > 0.f) ? u0 : 0.2f * u0;  v0 = (v0 > 0.f) ? v0 : 0.2f * v0;
        float p0 = u0 * a.x + v0 * a.y;
        p0 += __shfl_xor(p0, 1, 32);
        p0 += __shfl_xor(p0, 2, 32);
        p0 += __shfl_xor(p0, 4, 32);
        p0 += __shfl_xor(p0, 8, 32);
        p0 += __shfl_xor(p0, 16, 32);
        float mn0 = fmaxf(m0, p0);
        float sc0 = __expf(m0 - mn0), w0 = __expf(p0 - mn0);
        d0 = d0 * sc0 + w0;
        ax0 = ax0 * sc0 + w0 * xs0.x;
        ay0 = ay0 * sc0 + w0 * xs0.y;
        m0 = mn0;
    }
    float mm = fmaxf(m0, m1);
    float s0 = __expf(m0 - mm), s1 = __expf(m1 - mm);
    float den = d0 * s0 + d1 * s1;
    float ax = ax0 * s0 + ax1 * s1;
    float ay = ay0 * s0 + ay1 * s1;

    float2 bv = *(const float2*)(bias + lane * 2);
    float inv = 1.f / den;
    float ox = ax * inv + bv.x, oy = ay * inv + bv.y;
    if (do_relu) { ox = fmaxf(ox, 0.f); oy = fmaxf(oy, 0.f); }
    *(float2*)(out + (size_t)n * 128 + lane * 2) = make_float2(ox, oy);
}

// ---------------- LSTM weight packing (fallback path) ----------------
__global__ void build_wq_k(const float* __restrict__ Wih, const float* __restrict__ Whh,
                           float4* __restrict__ WQa, float4* __restrict__ WQb) {
    int id = blockIdx.x * 256 + threadIdx.x;
    if (id < 64 * 256) {
        int kp = id >> 8, t = id & 255;
        int j1 = t, j2 = t + 256;
        WQa[id] = make_float4(Wih[(size_t)j1 * 128 + 2 * kp], Whh[(size_t)j1 * 128 + 2 * kp],
                              Wih[(size_t)j1 * 128 + 2 * kp + 1], Whh[(size_t)j1 * 128 + 2 * kp + 1]);
        WQb[id] = make_float4(Wih[(size_t)j2 * 128 + 2 * kp], Whh[(size_t)j2 * 128 + 2 * kp],
                              Wih[(size_t)j2 * 128 + 2 * kp + 1], Whh[(size_t)j2 * 128 + 2 * kp + 1]);
    }
}

// ---------------- bf16 B-fragment pack of Whh (LSTM MFMA) ----------------
__global__ void build_bfrag_k(const float* __restrict__ Whh, ushort* __restrict__ Bfrag) {
    int id = blockIdx.x * 256 + threadIdx.x;    // 65536 ids
    if (id < 65536) {
        int j = id & 7, lane = (id >> 3) & 63, kt = (id >> 9) & 3, tile = id >> 11;
        int gate = tile * 16 + (lane & 15);
        int k = kt * 32 + ((lane >> 4) << 3) + j;
        Bfrag[id] = f2bf(Whh[(size_t)gate * 128 + k]);
    }
}

// ---- fallback LSTM (round-3, small-ws only) ----
#define LSTM_GROUP(buf, gbase)                                                     \
    _Pragma("unroll")                                                              \
    for (int i_ = 0; i_ < 4; i_++) {                                               \
        const int kp_ = (gbase) * 4 + i_;                                          \
        const float4 qa_ = buf[i_];                                                \
        const float4 qb_ = buf[4 + i_];                                            \
        _Pragma("unroll")                                                          \
        for (int n_ = 0; n_ < 4; n_++) {                                           \
            const float sx0_ = rdlane(xr[n_].x, kp_);                              \
            const float sh0_ = rdlane(hr[n_].x, kp_);                              \
            const float sx1_ = rdlane(xr[n_].y, kp_);                              \
            const float sh1_ = rdlane(hr[n_].y, kp_);                              \
            acc1[n_] += sx0_ * qa_.x + sh0_ * qa_.y + sx1_ * qa_.z + sh1_ * qa_.w; \
            acc2[n_] += sx0_ * qb_.x + sh0_ * qb_.y + sx1_ * qb_.z + sh1_ * qb_.w; \
        }                                                                          \
    }

__global__ __launch_bounds__(256, 1) void lstm_k(
    float* __restrict__ mu, const float4* __restrict__ WQa, const float4* __restrict__ WQb,
    const float* __restrict__ bih, const float* __restrict__ bhh,
    const float* __restrict__ h0, const float* __restrict__ c0,
    float* __restrict__ hT, float* __restrict__ cT)
{
    const int t = threadIdx.x, lane = t & 63;
    const int n0 = blockIdx.x * 4;
    __shared__ float hsh[4][128];
    __shared__ float gsh[4][512];
    const float b1 = bih[t] + bhh[t];
    const float b2 = bih[t + 256] + bhh[t + 256];
    float creg[2];
#pragma unroll
    for (int q = 0; q < 2; q++) {
        int id = t + 256 * q;
        creg[q] = c0[(size_t)(n0 + (id >> 7)) * 128 + (id & 127)];
    }
    for (int i = t; i < 512; i += 256)
        hsh[i >> 7][i & 127] = h0[(size_t)(n0 + (i >> 7)) * 128 + (i & 127)];

    const float4* pA = WQa + t;
    const float4* pB = WQb + t;

    float2 xr[4], xnx[4];
#pragma unroll
    for (int n = 0; n < 4; n++)
        xr[n] = *(const float2*)(mu + (size_t)n0 * 128 + n * 128 + lane * 2);
    __syncthreads();

    for (int s = 0; s < SQ; s++) {
        float* xrow = mu + ((size_t)s * NN + n0) * 128;
        float2 hr[4];
#pragma unroll
        for (int n = 0; n < 4; n++) hr[n] = *(const float2*)(&hsh[n][lane * 2]);

        float4 bufA[8], bufB[8];
#pragma unroll
        for (int i = 0; i < 4; i++) { bufA[i] = pA[i * 256]; bufA[4 + i] = pB[i * 256]; }

        if (s + 1 < SQ) {
            const float* xrow2 = mu + ((size_t)(s + 1) * NN + n0) * 128;
#pragma unroll
            for (int n = 0; n < 4; n++) xnx[n] = *(const float2*)(xrow2 + n * 128 + lane * 2);
        }

        float acc1[4], acc2[4];
#pragma unroll
        for (int n = 0; n < 4; n++) { acc1[n] = b1; acc2[n] = b2; }

        for (int g = 0; g < 16; g += 2) {
#pragma unroll
            for (int i = 0; i < 4; i++) {
                bufB[i]     = pA[((g + 1) * 4 + i) * 256];
                bufB[4 + i] = pB[((g + 1) * 4 + i) * 256];
            }
            LSTM_GROUP(bufA, g)
            if (g < 14) {
#pragma unroll
                for (int i = 0; i < 4; i++) {
                    bufA[i]     = pA[((g + 2) * 4 + i) * 256];
                    bufA[4 + i] = pB[((g + 2) * 4 + i) * 256];
                }
            }
            LSTM_GROUP(bufB, g + 1)
        }

#pragma unroll
        for (int n = 0; n < 4; n++) { gsh[n][t] = acc1[n]; gsh[n][t + 256] = acc2[n]; }
        __syncthreads();
#pragma unroll
        for (int q = 0; q < 2; q++) {
            int id = t + 256 * q;
            int n = id >> 7, e = id & 127;
            float iv = gsh[n][e], fv = gsh[n][128 + e];
            float gv = gsh[n][256 + e], ov = gsh[n][384 + e];
            float c = sigm(fv) * creg[q] + sigm(iv) * tanh_f(gv);
            float h = sigm(ov) * tanh_f(c);
            creg[q] = c;
            hsh[n][e] = h;
            xrow[n * 128 + e] = h;
            if (s == SQ - 1) {
                hT[(size_t)(n0 + n) * 128 + e] = h;
                cT[(size_t)(n0 + n) * 128 + e] = c;
            }
        }
#pragma unroll
        for (int n = 0; n < 4; n++) xr[n] = xnx[n];
        __syncthreads();
    }
}

// ---------------- MFMA LSTM v5 (big-ws path) ----------------
// r6's proven 63 blocks x 16 nodes full-MFMA shape (184us), plus:
//  - ping-pong h buffers -> ONE barrier/step (epilogue writes the other buffer)
//  - xC register prefetch one step AHEAD (loads covered by a full step of
//    MFMA+epilogue instead of ~300cyc) — scalar loads are 4x64B/wave-coalesced
//  - cheap inf-safe tanh
// NO LDS staging of xC (r9's 12.2M bank conflicts killed that).
__global__ __launch_bounds__(256, 1) void lstm6_k(
    float* __restrict__ mu, const float* __restrict__ xC,
    const ushort* __restrict__ Bfrag,
    const float* __restrict__ h0, const float* __restrict__ c0,
    float* __restrict__ hT, float* __restrict__ cT)
{
    const int t = threadIdx.x;
    const int w = t >> 6, lane = t & 63;
    const int quad = lane >> 4, col = lane & 15;
    const int n0 = blockIdx.x * 16;
    const int c_ = w * 16 + col;                  // 0..63 channel-within-64

    __shared__ __align__(16) ushort hbuf[2][2][16 * 136];   // [pingpong][hi/lo]

    // B fragments -> registers (constant all 64 steps)
    short8 bf[8][4];
#pragma unroll
    for (int q = 0; q < 8; q++)
#pragma unroll
        for (int kt = 0; kt < 4; kt++) {
            int tile = q * 4 + w;
            bf[q][kt] = *(const short8*)(Bfrag + (((tile * 4 + kt) * 64 + lane) << 3));
        }

    // init h into both buffers, c into regs
    for (int i = t; i < 2048; i += 256) {
        int node = i >> 7, e = i & 127;
        int gn = n0 + node;
        float v = (gn < NN) ? h0[(size_t)gn * 128 + e] : 0.f;
        ushort hh = f2bf(v), hl = f2bf(v - bf2f(hh));
        hbuf[0][0][node * 136 + e] = hh; hbuf[0][1][node * 136 + e] = hl;
        hbuf[1][0][node * 136 + e] = hh; hbuf[1][1][node * 136 + e] = hl;
    }
    float cst[8];
#pragma unroll
    for (int q = 0; q < 2; q++)
#pragma unroll
        for (int r = 0; r < 4; r++) {
            int gn = n0 + quad * 4 + r;
            cst[q * 4 + r] = (gn < NN) ? c0[(size_t)gn * 128 + (q * 64 + c_)] : 0.f;
        }

    // preload step-0 xC gate preacts (gate index = q*64 + c_, q covers all 8 groups)
    float xcr[8][4], xcn[8][4];
#pragma unroll
    for (int q = 0; q < 8; q++)
#pragma unroll
        for (int r = 0; r < 4; r++) {
            int gn = n0 + quad * 4 + r; if (gn >= NN) gn = NN - 1;
            xcr[q][r] = xC[(size_t)gn * 512 + (q * 64 + c_)];
        }
    __syncthreads();

    int p = 0;
    for (int s = 0; s < SQ; s++) {
        // 1. issue next step's xC loads — consumed NEXT iteration (full-step cover)
        if (s + 1 < SQ) {
            const float* xn = xC + (size_t)(s + 1) * (NN * 512);
#pragma unroll
            for (int q = 0; q < 8; q++)
#pragma unroll
                for (int r = 0; r < 4; r++) {
                    int gn = n0 + quad * 4 + r; if (gn >= NN) gn = NN - 1;
                    xcn[q][r] = xn[(size_t)gn * 512 + (q * 64 + c_)];
                }
        }

        // 2. A fragments from current h buffer
        short8 ahi[4], alo[4];
#pragma unroll
        for (int kt = 0; kt < 4; kt++) {
            ahi[kt] = *(const short8*)(&hbuf[p][0][col * 136 + kt * 32 + quad * 8]);
            alo[kt] = *(const short8*)(&hbuf[p][1][col * 136 + kt * 32 + quad * 8]);
        }

        // 3. MFMA block
        f32x4 acc[8];
#pragma unroll
        for (int q = 0; q < 8; q++) acc[q] = (f32x4){0.f, 0.f, 0.f, 0.f};
#pragma unroll
        for (int kt = 0; kt < 4; kt++) {
#pragma unroll
            for (int q = 0; q < 8; q++) {
                acc[q] = __builtin_amdgcn_mfma_f32_16x16x32_bf16(ahi[kt], bf[q][kt], acc[q], 0, 0, 0);
                acc[q] = __builtin_amdgcn_mfma_f32_16x16x32_bf16(alo[kt], bf[q][kt], acc[q], 0, 0, 0);
            }
        }

        // 4. epilogue -> OTHER h buffer; single barrier at end of step
        float* mus = mu + (size_t)s * (NN * 128);
        const int pn = p ^ 1;
#pragma unroll
        for (int q = 0; q < 2; q++)
#pragma unroll
            for (int r = 0; r < 4; r++) {
                float iv = acc[q][r]     + xcr[q][r];
                float fv = acc[q + 2][r] + xcr[q + 2][r];
                float gv = acc[q + 4][r] + xcr[q + 4][r];
                float ov = acc[q + 6][r] + xcr[q + 6][r];
                float c = sigm(fv) * cst[q * 4 + r] + sigm(iv) * tanh2(gv);
                float h = sigm(ov) * tanh2(c);
                cst[q * 4 + r] = c;
                int node = quad * 4 + r;
                int gn = n0 + node;
                int e = q * 64 + c_;
                ushort hh = f2bf(h);
                hbuf[pn][0][node * 136 + e] = hh;
                hbuf[pn][1][node * 136 + e] = f2bf(h - bf2f(hh));
                if (gn < NN) {
                    mus[(size_t)gn * 128 + e] = h;
                    if (s == SQ - 1) {
                        hT[(size_t)gn * 128 + e] = h;
                        cT[(size_t)gn * 128 + e] = c;
                    }
                }
            }
#pragma unroll
        for (int q = 0; q < 8; q++)
#pragma unroll
            for (int r = 0; r < 4; r++) xcr[q][r] = xcn[q][r];
        p = pn;
        __syncthreads();
    }
}

// ---------------- head: meanpool -> gs -> A[s] (r7 version — proven) ----------------
__global__ __launch_bounds__(256) void meanpool_gs_k(
    const float* __restrict__ mu, const float* __restrict__ W6,
    const float* __restrict__ b6, const float* __restrict__ w5,
    float* __restrict__ A)
{
    const int s = blockIdx.x, t = threadIdx.x;
    const int ch = t & 127, half = t >> 7;
    __shared__ float mp[128];
    __shared__ float red[256];
    float acc = 0.f;
    for (int n = half * 500; n < (half + 1) * 500; n++)
        acc += mu[((size_t)s * NN + n) * 128 + ch];
    red[t] = acc;
    __syncthreads();
    if (t < 128) mp[t] = (red[t] + red[t + 128]) * 0.001f;
    __syncthreads();
    float g = 0.f;
    if (t < 128) {
        g = b6[t];
        for (int k = 0; k < 128; k++) g += mp[k] * W6[(size_t)k * 128 + t];
        g = fmaxf(g, 0.f) * w5[t];
    }
    red[t] = g;
    __syncthreads();
    for (int o = 128; o > 0; o >>= 1) {
        if (t < o) red[t] += red[t + o];
        __syncthreads();
    }
    if (t == 0) A[s] = red[0];
}

// ---------------- head: logit2[row] ----------------
__global__ __launch_bounds__(256) void rowdot_k(
    const float* __restrict__ la, const float* __restrict__ w5,
    const float* __restrict__ b5, const float* __restrict__ A,
    float* __restrict__ out)
{
    const int lane = threadIdx.x & 63;
    const int row = blockIdx.x * 4 + (threadIdx.x >> 6);
    float2 v = *(const float2*)(la + (size_t)row * 128 + lane * 2);
    float2 w = *(const float2*)(w5 + 128 + lane * 2);
    float x = fmaxf(v.x, 0.f) * w.x + fmaxf(v.y, 0.f) * w.y;
#pragma unroll
    for (int o = 32; o; o >>= 1) x += __shfl_down(x, o);
    if (lane == 0) out[row] = x + A[row / NN] + b5[0];
}

// ---------------- masked softmax per sequence step ----------------
__device__ __forceinline__ bool reach_at(const void* reach, int mode, int idx) {
    if (mode == 0) return ((const int*)reach)[idx] != 0;
    if (mode == 1) return ((const unsigned char*)reach)[idx] != 0;
    return ((const float*)reach)[idx] != 0.f;
}
__global__ __launch_bounds__(256) void softmax_k(
    const float* __restrict__ lg, const void* __restrict__ reach,
    const int* __restrict__ mode, float* __restrict__ prob)
{
    const int s = blockIdx.x, t = threadIdx.x;
    const int m = *mode;
    __shared__ float red[256];
    float mx = -1e30f;
    for (int i = t; i < NN; i += 256) {
        int idx = s * NN + i;
        if (reach_at(reach, m, idx)) mx = fmaxf(mx, lg[idx]);
    }
    red[t] = mx;
    __syncthreads();
    for (int o = 128; o; o >>= 1) {
        if (t < o) red[t] = fmaxf(red[t], red[t + o]);
        __syncthreads();
    }
    mx = red[0];
    __syncthreads();
    float sum = 0.f;
    for (int i = t; i < NN; i += 256) {
        int idx = s * NN + i;
        float v = reach_at(reach, m, idx) ? __expf(lg[idx] - mx) : 0.f;
        prob[idx] = v;
        sum += v;
    }
    red[t] = sum;
    __syncthreads();
    for (int o = 128; o; o >>= 1) {
        if (t < o) red[t] += red[t + o];
        __syncthreads();
    }
    float inv = 1.f / red[0];
    for (int i = t; i < NN; i += 256) prob[s * NN + i] *= inv;
}

// ---------------- driver ----------------
extern "C" void kernel_launch(void* const* d_in, const int* in_sizes, int n_in,
                              void* d_out, int out_size, void* d_ws, size_t ws_size,
                              hipStream_t stream) {
    const float* nfm   = (const float*)d_in[0];
    const int*   ei    = (const int*)d_in[1];
    const void*  reach = d_in[2];
    const float* h0    = (const float*)d_in[3];
    const float* c0    = (const float*)d_in[4];
    const float* W1    = (const float*)d_in[5];
    const float* b1    = (const float*)d_in[6];
    const float* att1  = (const float*)d_in[7];
    const float* bias1 = (const float*)d_in[8];
    const float* Wl    = (const float*)d_in[9];
    const float* bl    = (const float*)d_in[10];
    const float* attl  = (const float*)d_in[11];
    const float* biasl = (const float*)d_in[12];
    const float* Wih   = (const float*)d_in[13];
    const float* Whh   = (const float*)d_in[14];
    const float* bih   = (const float*)d_in[15];
    const float* bhh   = (const float*)d_in[16];
    const float* W6    = (const float*)d_in[17];
    const float* b6    = (const float*)d_in[18];
    const float* W7    = (const float*)d_in[19];
    const float* b7    = (const float*)d_in[20];
    const float* w5    = (const float*)d_in[21];
    const float* b5    = (const float*)d_in[22];

    char* ws = (char*)d_ws;
    const bool bigws = (ws_size >= WS2_NEED);

    float*  xA     = (float*)(ws + WS_XA);
    float*  xB     = (float*)(ws + WS_XB);
    int*    rowptr = (int*)(ws + WS_ROWPTR);
    int*    cursor = (int*)(ws + WS_CURSOR);
    int*    srcs   = (int*)(ws + WS_SRCS);
    int*    incl   = (int*)(ws + WS_INCL);
    int*    bsum   = (int*)(ws + WS_BSUM);
    int*    boff   = (int*)(ws + WS_BOFF);
    int*    modep  = bigws ? (int*)(ws + WS2_MODE)     : (int*)(ws + WS_MODE);
    float*  As     = bigws ? (float*)(ws + WS2_AS)     : (float*)(ws + WS_AS);
    float*  logit2 = bigws ? (float*)(ws + WS2_LOGIT2) : (float*)(ws + WS_LOGIT2);
    // big-ws extras
    float*  xC     = (float*)(ws + WS2_XC);
    ushort* Bfrag  = (ushort*)(ws + WS2_BFRAG);
    ushort* ghi    = (ushort*)(ws + WS2_GHI);
    ushort* glo    = (ushort*)(ws + WS2_GLO);
    float*  b512   = (float*)(ws + WS2_B512);
    // fallback extras
    float4* WQa    = (float4*)(ws + WS_WQA);
    float4* WQb    = (float4*)(ws + WS_WQB);

    float* prob = (float*)d_out;
    float* hT   = (float*)d_out + 64000;
    float* cT   = (float*)d_out + 192000;

    // setup
    detect_mode_k<<<1, 256, 0, stream>>>((const unsigned char*)reach, modep);
    zero_ints_k<<<250, 256, 0, stream>>>(cursor, NT);
    hist_k<<<2250, 256, 0, stream>>>(ei, cursor);
    scan1_k<<<250, 256, 0, stream>>>(cursor, incl, bsum);
    scan2_k<<<1, 256, 0, stream>>>(bsum, boff);
    scan3_k<<<250, 256, 0, stream>>>(incl, boff, rowptr, cursor);
    fill_k<<<2250, 256, 0, stream>>>(ei, cursor, srcs);
    if (bigws) {
        build_bfrag_k<<<256, 256, 0, stream>>>(Whh, Bfrag);
        bias512_k<<<2, 256, 0, stream>>>(bih, bhh, b512);
        build_gfrag_k<<<32, 256, 0, stream>>>(W1, 128, 1, 64, ghi + G_W1, glo + G_W1, 8192);
        for (int i = 0; i < 4; i++)
            build_gfrag_k<<<64, 256, 0, stream>>>(Wl + (size_t)i * 16384, 128, 1, 128,
                                                  ghi + G_WL + i * 16384, glo + G_WL + i * 16384, 16384);
        build_gfrag_k<<<256, 256, 0, stream>>>(Wih, 1, 128, 128, ghi + G_PROJ, glo + G_PROJ, 65536);
        build_gfrag_k<<<64, 256, 0, stream>>>(W7, 128, 1, 128, ghi + G_W7, glo + G_W7, 16384);
    } else {
        build_wq_k<<<64, 256, 0, stream>>>(Wih, Whh, WQa, WQb);
    }

    // 5 GATv2 layers: gemm (x->xB), fused logits+softmax+aggregate (xB->xA)
    for (int l = 0; l < 5; l++) {
        if (bigws) {
            if (l == 0)
                gemm_mf<2><<<dim3(1000, 1), 256, 0, stream>>>(nfm, ghi + G_W1, glo + G_W1, b1, xB, 128);
            else
                gemm_mf<4><<<dim3(1000, 1), 256, 0, stream>>>(xA, ghi + G_WL + (l - 1) * 16384,
                                                              glo + G_WL + (l - 1) * 16384,
                                                              bl + (l - 1) * 128, xB, 128);
        } else {
            if (l == 0)
                gemm3<64><<<500, 256, 0, stream>>>(nfm, W1, b1, xB);
            else
                gemm3<128><<<500, 256, 0, stream>>>(xA, Wl + (size_t)(l - 1) * 128 * 128,
                                                    bl + (l - 1) * 128, xB);
        }
        const float* att  = (l == 0) ? att1  : attl  + (l - 1) * 128;
        const float* bias = (l == 0) ? bias1 : biasl + (l - 1) * 128;
        gat_fused_k<<<16000, 256, 0, stream>>>(xB, rowptr, srcs, att, bias, xA,
                                               (l < 4) ? 1 : 0);
    }

    // LSTM
    if (bigws) {
        // xC = mu @ Wih^T + (bih+bhh), row-major (full-line writes)
        gemm_mf<4><<<dim3(1000, 4), 256, 0, stream>>>(xA, ghi + G_PROJ, glo + G_PROJ, b512, xC, 512);
        lstm6_k<<<63, 256, 0, stream>>>(xA, xC, Bfrag, h0, c0, hT, cT);
    } else {
        lstm_k<<<250, 256, 0, stream>>>(xA, WQa, WQb, bih, bhh, h0, c0, hT, cT);
    }

    // head
    meanpool_gs_k<<<64, 256, 0, stream>>>(xA, W6, b6, w5, As);
    if (bigws)
        gemm_mf<4><<<dim3(1000, 1), 256, 0, stream>>>(xA, ghi + G_W7, glo + G_W7, b7, xB, 128);
    else
        gemm3<128><<<500, 256, 0, stream>>>(xA, W7, b7, xB);
    rowdot_k<<<16000, 256, 0, stream>>>(xB, w5, b5, As, logit2);
    softmax_k<<<64, 256, 0, stream>>>(logit2, reach, modep, prob);
}